// Round 3
// baseline (1846.762 us; speedup 1.0000x reference)
//
#include <hip/hip_runtime.h>
#include <hip/hip_bf16.h>
#include <math.h>

// Problem constants (B,S,D,H) = (2,2048,1024,16), DK=64
#define B_ 2
#define S_ 2048
#define D_ 1024
#define H_ 16
#define DK_ 64

// log2(10000)/32
#define ROPE_C 0.4152410118609203f

// ---------------------------------------------------------------------------
// Tiled GEMM: C[M,N] = X[M,K] @ W[K,N] + bias   (all fp32 I/O)
//   MODE 0: write fp32 out laid out [B,H,S,DK]            (V projection)
//   MODE 1: apply reference RoPE, write fp32 [B,H,S,DK]   (Q,K projections)
//   MODE 2: write fp32 out laid out [M,N]                 (output projection)
// M=4096, N=K=1024. Block tile 64x64, K-step 16, 256 threads, 4x4 per thread.
// ---------------------------------------------------------------------------
template <int MODE>
__global__ __launch_bounds__(256) void gemm_k(const float* __restrict__ X,
                                              const float* __restrict__ W,
                                              const float* __restrict__ bias,
                                              float* __restrict__ outp) {
  const int N = D_, K = D_;
  constexpr int BM = 64, BN = 64, BK = 16;
  __shared__ float Xs[BK][BM + 4];
  __shared__ float Ws[BK][BN + 4];

  const int t = threadIdx.x;
  const int m0 = blockIdx.x * BM;
  const int n0 = blockIdx.y * BN;
  const int r0 = (t >> 4) << 2;  // 0..60 step 4
  const int c0 = (t & 15) << 2;  // 0..60 step 4

  float acc[4][4] = {};

  for (int k0 = 0; k0 < K; k0 += BK) {
    #pragma unroll
    for (int e = t; e < BM * BK; e += 256) {
      int r = e >> 4, c = e & 15;
      Xs[c][r] = X[(size_t)(m0 + r) * K + (k0 + c)];
    }
    #pragma unroll
    for (int e = t; e < BK * BN; e += 256) {
      int r = e >> 6, c = e & 63;
      Ws[r][c] = W[(size_t)(k0 + r) * N + (n0 + c)];
    }
    __syncthreads();
    #pragma unroll
    for (int kk = 0; kk < BK; ++kk) {
      float a0 = Xs[kk][r0 + 0], a1 = Xs[kk][r0 + 1];
      float a2 = Xs[kk][r0 + 2], a3 = Xs[kk][r0 + 3];
      float b0 = Ws[kk][c0 + 0], b1 = Ws[kk][c0 + 1];
      float b2 = Ws[kk][c0 + 2], b3 = Ws[kk][c0 + 3];
      acc[0][0] += a0 * b0; acc[0][1] += a0 * b1; acc[0][2] += a0 * b2; acc[0][3] += a0 * b3;
      acc[1][0] += a1 * b0; acc[1][1] += a1 * b1; acc[1][2] += a1 * b2; acc[1][3] += a1 * b3;
      acc[2][0] += a2 * b0; acc[2][1] += a2 * b1; acc[2][2] += a2 * b2; acc[2][3] += a2 * b3;
      acc[3][0] += a3 * b0; acc[3][1] += a3 * b1; acc[3][2] += a3 * b2; acc[3][3] += a3 * b3;
    }
    __syncthreads();
  }

  if constexpr (MODE == 2) {
    #pragma unroll
    for (int i = 0; i < 4; ++i) {
      int m = m0 + r0 + i;
      #pragma unroll
      for (int jj = 0; jj < 4; ++jj) {
        int n = n0 + c0 + jj;
        outp[(size_t)m * N + n] = acc[i][jj] + bias[n];
      }
    }
  } else {
    #pragma unroll
    for (int i = 0; i < 4; ++i) {
      int m = m0 + r0 + i;
      int b = m >> 11;      // / S_
      int s = m & (S_ - 1); // % S_
      float v[4];
      #pragma unroll
      for (int jj = 0; jj < 4; ++jj) v[jj] = acc[i][jj] + bias[n0 + c0 + jj];
      if constexpr (MODE == 1) {
        // Reference RoPE (interleaved, frequency-mixed):
        //  out[2j]   = x[2j]*cos(th(2j))   - x[2j+1]*sin(th(2j+1))
        //  out[2j+1] = x[2j]*sin(th(2j))   + x[2j+1]*cos(th(2j+1))
        //  th(i) = pos * 10000^(-(i mod 32)/32)
        float pos = (float)s;
        #pragma unroll
        for (int jj = 0; jj < 4; jj += 2) {
          int dk_e = (n0 + c0 + jj) & 63;
          int dk_o = dk_e + 1;
          float th_a = pos * exp2f(-(float)(dk_e & 31) * ROPE_C);
          float th_b = pos * exp2f(-(float)(dk_o & 31) * ROPE_C);
          float sa, ca, sb, cb;
          sincosf(th_a, &sa, &ca);
          sincosf(th_b, &sb, &cb);
          float xe = v[jj], xo = v[jj + 1];
          v[jj]     = xe * ca - xo * sb;
          v[jj + 1] = xe * sa + xo * cb;
        }
      }
      #pragma unroll
      for (int jj = 0; jj < 4; ++jj) {
        int n = n0 + c0 + jj;
        int h = n >> 6, dk = n & 63;
        outp[(((size_t)b * H_ + h) * S_ + s) * DK_ + dk] = v[jj];
      }
    }
  }
}

// ---------------------------------------------------------------------------
// Flash-style causal attention over fp32 Q/K/V in [B*H, S, DK] layout.
// Grid: (B*H, S/64). Block: 256 threads. Q tile 64 rows, K/V tiles 64 rows.
// K and V share one LDS buffer. Q pre-scaled by 1/sqrt(DK)=0.125.
// Output ctx is fp32 [B, S, D].
// ---------------------------------------------------------------------------
__global__ __launch_bounds__(256) void attn_k(const float* __restrict__ qf,
                                              const float* __restrict__ kf,
                                              const float* __restrict__ vf,
                                              float* __restrict__ ctx) {
  __shared__ float Qs[64][68];
  __shared__ float KVs[64][68];
  __shared__ float Ps[64][68];
  __shared__ float mrow[64], lrow[64], arow[64];

  const int t = threadIdx.x;
  const int bh = blockIdx.x;  // 0..31
  const int qt = blockIdx.y;  // 0..31
  const int i0 = qt << 6;
  const size_t base = (size_t)bh * S_ * DK_;

  for (int e = t; e < 64 * 64; e += 256) {
    int r = e >> 6, c = e & 63;
    Qs[r][c] = qf[base + (size_t)(i0 + r) * DK_ + c] * 0.125f;
  }
  if (t < 64) { mrow[t] = -INFINITY; lrow[t] = 0.f; }

  float o[16] = {};
  const int r = t >> 2;         // output row 0..63
  const int cg = (t & 3) << 4;  // output col group: 16 cols
  __syncthreads();

  for (int jt = 0; jt <= qt; ++jt) {
    const int j0 = jt << 6;
    for (int e = t; e < 64 * 64; e += 256) {
      int rr = e >> 6, c = e & 63;
      KVs[rr][c] = kf[base + (size_t)(j0 + rr) * DK_ + c];
    }
    __syncthreads();
    for (int j = cg; j < cg + 16; ++j) {
      float s = 0.f;
      #pragma unroll
      for (int d = 0; d < 64; ++d) s += Qs[r][d] * KVs[j][d];
      Ps[r][j] = ((j0 + j) > (i0 + r)) ? -1e30f : s;
    }
    __syncthreads();
    for (int e = t; e < 64 * 64; e += 256) {
      int rr = e >> 6, c = e & 63;
      KVs[rr][c] = vf[base + (size_t)(j0 + rr) * DK_ + c];
    }
    if (t < 64) {
      float m_old = mrow[t], l = lrow[t];
      float m_new = m_old;
      for (int j = 0; j < 64; ++j) m_new = fmaxf(m_new, Ps[t][j]);
      float alpha = expf(m_old - m_new);  // expf(-inf)=0 on first tile
      l *= alpha;
      for (int j = 0; j < 64; ++j) {
        float p = expf(Ps[t][j] - m_new);
        Ps[t][j] = p;
        l += p;
      }
      mrow[t] = m_new; lrow[t] = l; arow[t] = alpha;
    }
    __syncthreads();
    {
      float alpha = arow[r];
      #pragma unroll
      for (int cc = 0; cc < 16; ++cc) o[cc] *= alpha;
      for (int j = 0; j < 64; ++j) {
        float p = Ps[r][j];
        #pragma unroll
        for (int cc = 0; cc < 16; ++cc) o[cc] += p * KVs[j][cg + cc];
      }
    }
    __syncthreads();
  }

  const float inv_l = 1.f / lrow[r];
  const int b = bh / H_, h = bh % H_;
  const size_t obase = ((size_t)b * S_ + (i0 + r)) * D_ + h * DK_ + cg;
  #pragma unroll
  for (int cc = 0; cc < 16; ++cc) ctx[obase + cc] = o[cc] * inv_l;
}

// ---------------------------------------------------------------------------
extern "C" void kernel_launch(void* const* d_in, const int* in_sizes, int n_in,
                              void* d_out, int out_size, void* d_ws, size_t ws_size,
                              hipStream_t stream) {
  const float* q_in = (const float*)d_in[0];
  const float* k_in = (const float*)d_in[1];
  const float* v_in = (const float*)d_in[2];
  const float* Wq = (const float*)d_in[3];
  const float* bq = (const float*)d_in[4];
  const float* Wk = (const float*)d_in[5];
  const float* bk = (const float*)d_in[6];
  const float* Wv = (const float*)d_in[7];
  const float* bv = (const float*)d_in[8];
  const float* Wo = (const float*)d_in[9];
  const float* bo = (const float*)d_in[10];

  const size_t NE = (size_t)B_ * S_ * D_;  // 4,194,304
  float* qf = (float*)d_ws;
  float* kf = qf + NE;
  float* vf = kf + NE;
  float* ctx = vf + NE;
  // total ws use: 4 * NE * 4 B = 67.1 MB

  dim3 gg((B_ * S_) / 64, D_ / 64);  // (64, 16)
  gemm_k<1><<<gg, 256, 0, stream>>>(q_in, Wq, bq, qf);
  gemm_k<1><<<gg, 256, 0, stream>>>(k_in, Wk, bk, kf);
  gemm_k<0><<<gg, 256, 0, stream>>>(v_in, Wv, bv, vf);

  attn_k<<<dim3(B_ * H_, S_ / 64), 256, 0, stream>>>(qf, kf, vf, ctx);

  gemm_k<2><<<gg, 256, 0, stream>>>(ctx, Wo, bo, (float*)d_out);
}

// Round 4
// 471.328 us; speedup vs baseline: 3.9182x; 3.9182x over previous
//
#include <hip/hip_runtime.h>
#include <hip/hip_bf16.h>
#include <math.h>

// (B,S,D,H) = (2,2048,1024,16), DK=64
#define B_ 2
#define S_ 2048
#define D_ 1024
#define H_ 16
#define DK_ 64

#define ROPE_C 0.4152410118609203f   // log2(10000)/32
#define LOG2E 1.4426950408889634f

typedef float f4 __attribute__((ext_vector_type(4)));
typedef short s8 __attribute__((ext_vector_type(8)));

__device__ __forceinline__ ushort f2b(float f) {
  union { float f; uint u; } v; v.f = f;
  uint u = v.u + 0x7fffu + ((v.u >> 16) & 1u);
  return (ushort)(u >> 16);
}

// ---------------------------------------------------------------------------
// Prep 1: fp32 -> bf16 flat convert (4M elems). 8 elems/thread.
// ---------------------------------------------------------------------------
__global__ __launch_bounds__(256) void conv_x(const float* __restrict__ in,
                                              ushort* __restrict__ out) {
  int idx = (blockIdx.x * 256 + threadIdx.x) * 8;
  float4 a = *(const float4*)&in[idx];
  float4 b = *(const float4*)&in[idx + 4];
  ushort tmp[8] = {f2b(a.x), f2b(a.y), f2b(a.z), f2b(a.w),
                   f2b(b.x), f2b(b.y), f2b(b.z), f2b(b.w)};
  *(uint4*)&out[idx] = *(uint4*)tmp;
}

// ---------------------------------------------------------------------------
// Prep 2: W fp32 [K=1024][N=1024] -> Wt bf16 [N][K]. 64x64 LDS tiles.
// ---------------------------------------------------------------------------
__global__ __launch_bounds__(256) void transpose_w(const float* __restrict__ W,
                                                   ushort* __restrict__ Wt) {
  __shared__ ushort T[64][65];
  const int t = threadIdx.x;
  const int k0 = blockIdx.x * 64, n0 = blockIdx.y * 64;
  #pragma unroll
  for (int i = 0; i < 16; ++i) {
    int e = t + i * 256, r = e >> 6, c = e & 63;
    T[c][r] = f2b(W[(size_t)(k0 + r) * D_ + n0 + c]);
  }
  __syncthreads();
  #pragma unroll
  for (int i = 0; i < 16; ++i) {
    int e = t + i * 256, r = e >> 6, c = e & 63;
    Wt[(size_t)(n0 + r) * D_ + k0 + c] = T[r][c];
  }
}

// ---------------------------------------------------------------------------
// MFMA GEMM: C[M=4096][n] = A[m][k=1024] (bf16) @ Wt[n][k] (bf16) + bias.
// BM=128, BN template, BK=32, 256 thr = 4 waves (2x2), wave = 64 x BN/2.
// MODE 0: fused QKV epilogue (RoPE for Q/K, V transposed store), N=3072,
//         A/bias selected per block by n0>>10.
// MODE 2: fp32 [M][N] + bias (final projection).
// ---------------------------------------------------------------------------
template <int BN, int MODE>
__global__ __launch_bounds__(256) void gemm_mfma(
    const ushort* __restrict__ A0, const ushort* __restrict__ A1,
    const ushort* __restrict__ A2, const ushort* __restrict__ Bt,
    const float* __restrict__ bb0, const float* __restrict__ bb1,
    const float* __restrict__ bb2,
    ushort* __restrict__ oq, ushort* __restrict__ ok, ushort* __restrict__ ov,
    float* __restrict__ oo) {
  constexpr int NT = BN / 32;  // n-tiles per wave
  __shared__ ushort As[128][40];
  __shared__ ushort Bs[BN][40];

  const int t = threadIdx.x, w = t >> 6, l = t & 63;
  const int m0 = blockIdx.x * 128, n0 = blockIdx.y * BN;
  const int wm = (w >> 1) * 64, wn = (w & 1) * (BN / 2);
  const int lm = l & 15, h8 = (l >> 4) * 8, q4 = (l >> 4) * 4;

  const ushort* A;
  const float* bias;
  int mat = 0;
  if constexpr (MODE == 0) {
    mat = n0 >> 10;
    A = (mat == 0) ? A0 : (mat == 1) ? A1 : A2;
    bias = (mat == 0) ? bb0 : (mat == 1) ? bb1 : bb2;
  } else {
    A = A0; bias = bb0;
  }

  f4 acc[4][NT];
  #pragma unroll
  for (int i = 0; i < 4; ++i)
    #pragma unroll
    for (int j = 0; j < NT; ++j) acc[i][j] = (f4){0.f, 0.f, 0.f, 0.f};

  for (int k0 = 0; k0 < D_; k0 += 32) {
    #pragma unroll
    for (int i = 0; i < 2; ++i) {
      int g = t + i * 256, r = g >> 2, c = (g & 3) * 8;
      *(uint4*)&As[r][c] = *(const uint4*)&A[(size_t)(m0 + r) * D_ + k0 + c];
    }
    #pragma unroll
    for (int i = 0; i < BN / 64; ++i) {
      int g = t + i * 256, r = g >> 2, c = (g & 3) * 8;
      *(uint4*)&Bs[r][c] = *(const uint4*)&Bt[(size_t)(n0 + r) * D_ + k0 + c];
    }
    __syncthreads();
    s8 af[4], bfr[NT];
    #pragma unroll
    for (int mt = 0; mt < 4; ++mt) af[mt] = *(const s8*)&As[wm + mt * 16 + lm][h8];
    #pragma unroll
    for (int nt = 0; nt < NT; ++nt) bfr[nt] = *(const s8*)&Bs[wn + nt * 16 + lm][h8];
    #pragma unroll
    for (int mt = 0; mt < 4; ++mt)
      #pragma unroll
      for (int nt = 0; nt < NT; ++nt)
        acc[mt][nt] = __builtin_amdgcn_mfma_f32_16x16x32_bf16(af[mt], bfr[nt], acc[mt][nt], 0, 0, 0);
    __syncthreads();
  }

  // ---- epilogue ----
  if constexpr (MODE == 2) {
    #pragma unroll
    for (int nt = 0; nt < NT; ++nt) {
      int n = n0 + wn + nt * 16 + lm;
      float bv = bias[n];
      #pragma unroll
      for (int mt = 0; mt < 4; ++mt)
        #pragma unroll
        for (int r = 0; r < 4; ++r)
          oo[(size_t)(m0 + wm + mt * 16 + q4 + r) * D_ + n] = acc[mt][nt][r] + bv;
    }
  } else {
    #pragma unroll
    for (int nt = 0; nt < NT; ++nt) {
      int nn = (n0 & 1023) + wn + nt * 16 + lm;  // 0..1023 within matrix
      int h = nn >> 6, dk = nn & 63;
      float bv = bias[(n0 & 1023) + wn + nt * 16 + lm];
      if (mat < 2) {
        // RoPE: even dk: x*cos(th_s) - px*sin(th_p); odd: x*cos(th_s) + px*sin(th_p)
        float invf_s = exp2f(-(float)(dk & 31) * ROPE_C);
        float invf_p = exp2f(-(float)((dk ^ 1) & 31) * ROPE_C);
        float sgn = (dk & 1) ? 1.f : -1.f;
        float scale = (mat == 0) ? 0.125f : 1.f;
        ushort* dst = (mat == 0) ? oq : ok;
        #pragma unroll
        for (int mt = 0; mt < 4; ++mt) {
          #pragma unroll
          for (int r = 0; r < 4; ++r) {
            int m = m0 + wm + mt * 16 + q4 + r;
            float x = acc[mt][nt][r] + bv;
            float px = __shfl_xor(x, 1);
            float pos = (float)(m & (S_ - 1));
            float cs = cosf(pos * invf_s), sp = sinf(pos * invf_p);
            float o = (x * cs + sgn * px * sp) * scale;
            int b = m >> 11, sr = m & (S_ - 1);
            dst[((size_t)(b * H_ + h) * S_ + sr) * DK_ + dk] = f2b(o);
          }
        }
      } else {
        // V: store transposed [bh][dk][S], pack 4 consecutive s
        #pragma unroll
        for (int mt = 0; mt < 4; ++mt) {
          int s0 = m0 + wm + mt * 16 + q4;
          int b = s0 >> 11, sr = s0 & (S_ - 1);
          uint lo = (uint)f2b(acc[mt][nt][0] + bv) | ((uint)f2b(acc[mt][nt][1] + bv) << 16);
          uint hi = (uint)f2b(acc[mt][nt][2] + bv) | ((uint)f2b(acc[mt][nt][3] + bv) << 16);
          uint2 pk; pk.x = lo; pk.y = hi;
          *(uint2*)&ov[((size_t)(b * H_ + h) * DK_ + dk) * S_ + sr] = pk;
        }
      }
    }
  }
}

// ---------------------------------------------------------------------------
// MFMA flash attention. Grid (32 bh, 32 qt), 256 thr = 4 waves x 16 Q-rows.
// Q pre-scaled. qf/kf: [bh][s][64] bf16; vtf: [bh][dk][2048] bf16.
// P: C-layout -> LDS -> A-layout round-trip (per-wave region, no barrier).
// ctx out: bf16 [B*S][1024].
// ---------------------------------------------------------------------------
__global__ __launch_bounds__(256) void attn_mfma(const ushort* __restrict__ qf,
                                                 const ushort* __restrict__ kf,
                                                 const ushort* __restrict__ vtf,
                                                 ushort* __restrict__ ctx) {
  __shared__ ushort Qs[64][72], Ks[64][72], Vts[64][72], Ps[64][72];

  const int t = threadIdx.x, w = t >> 6, l = t & 63;
  const int bh = blockIdx.x, qt = blockIdx.y;
  const int i0 = qt * 64;
  const int lm = l & 15, h8 = (l >> 4) * 8, q4 = (l >> 4) * 4, w16 = w * 16;
  const size_t base = (size_t)bh * S_ * DK_;

  #pragma unroll
  for (int i = 0; i < 2; ++i) {
    int g = t + i * 256, r = g >> 3, c = (g & 7) * 8;
    *(uint4*)&Qs[r][c] = *(const uint4*)&qf[base + (size_t)(i0 + r) * DK_ + c];
  }

  f4 O[4];
  #pragma unroll
  for (int i = 0; i < 4; ++i) O[i] = (f4){0.f, 0.f, 0.f, 0.f};
  float m_[4] = {-1e30f, -1e30f, -1e30f, -1e30f};
  float l_[4] = {0.f, 0.f, 0.f, 0.f};

  for (int jt = 0; jt <= qt; ++jt) {
    const int j0 = jt * 64;
    #pragma unroll
    for (int i = 0; i < 2; ++i) {
      int g = t + i * 256, r = g >> 3, c = (g & 7) * 8;
      *(uint4*)&Ks[r][c] = *(const uint4*)&kf[base + (size_t)(j0 + r) * DK_ + c];
      *(uint4*)&Vts[r][c] = *(const uint4*)&vtf[base + (size_t)r * S_ + j0 + c];
    }
    __syncthreads();  // covers Q staging on first iter

    // QK^T: sc[nt] = Q(16xDK) @ K^T(DK x 16nt)
    s8 aq0 = *(const s8*)&Qs[w16 + lm][h8];
    s8 aq1 = *(const s8*)&Qs[w16 + lm][h8 + 32];
    f4 sc[4];
    #pragma unroll
    for (int nt = 0; nt < 4; ++nt) {
      s8 b0 = *(const s8*)&Ks[nt * 16 + lm][h8];
      s8 b1 = *(const s8*)&Ks[nt * 16 + lm][h8 + 32];
      f4 a = (f4){0.f, 0.f, 0.f, 0.f};
      a = __builtin_amdgcn_mfma_f32_16x16x32_bf16(aq0, b0, a, 0, 0, 0);
      a = __builtin_amdgcn_mfma_f32_16x16x32_bf16(aq1, b1, a, 0, 0, 0);
      sc[nt] = a;
    }
    if (jt == qt) {  // causal mask on diagonal tile (i0 == j0)
      #pragma unroll
      for (int nt = 0; nt < 4; ++nt)
        #pragma unroll
        for (int r = 0; r < 4; ++r)
          if (nt * 16 + lm > w16 + q4 + r) sc[nt][r] = -1e30f;
    }
    // online softmax (rows owned by 16-lane groups; shfl_xor reduce)
    float rmax[4];
    #pragma unroll
    for (int r = 0; r < 4; ++r)
      rmax[r] = fmaxf(fmaxf(sc[0][r], sc[1][r]), fmaxf(sc[2][r], sc[3][r]));
    #pragma unroll
    for (int off = 1; off < 16; off <<= 1)
      #pragma unroll
      for (int r = 0; r < 4; ++r) rmax[r] = fmaxf(rmax[r], __shfl_xor(rmax[r], off));
    float alpha[4];
    #pragma unroll
    for (int r = 0; r < 4; ++r) {
      float mn = fmaxf(m_[r], rmax[r]);
      alpha[r] = exp2f((m_[r] - mn) * LOG2E);
      m_[r] = mn;
    }
    float rsum[4] = {0.f, 0.f, 0.f, 0.f};
    #pragma unroll
    for (int nt = 0; nt < 4; ++nt)
      #pragma unroll
      for (int r = 0; r < 4; ++r) {
        float p = exp2f((sc[nt][r] - m_[r]) * LOG2E);
        sc[nt][r] = p;
        rsum[r] += p;
      }
    #pragma unroll
    for (int off = 1; off < 16; off <<= 1)
      #pragma unroll
      for (int r = 0; r < 4; ++r) rsum[r] += __shfl_xor(rsum[r], off);
    #pragma unroll
    for (int r = 0; r < 4; ++r) l_[r] = l_[r] * alpha[r] + rsum[r];
    // P (C-layout) -> LDS bf16, per-wave region
    #pragma unroll
    for (int nt = 0; nt < 4; ++nt)
      #pragma unroll
      for (int r = 0; r < 4; ++r)
        Ps[w16 + q4 + r][nt * 16 + lm] = f2b(sc[nt][r]);
    #pragma unroll
    for (int nt = 0; nt < 4; ++nt)
      #pragma unroll
      for (int r = 0; r < 4; ++r) O[nt][r] *= alpha[r];
    // PV: O += P(16x64) @ V(64 x 16nt)   (Vt rows = dk)
    s8 ap0 = *(const s8*)&Ps[w16 + lm][h8];
    s8 ap1 = *(const s8*)&Ps[w16 + lm][h8 + 32];
    #pragma unroll
    for (int nt = 0; nt < 4; ++nt) {
      s8 v0 = *(const s8*)&Vts[nt * 16 + lm][h8];
      s8 v1 = *(const s8*)&Vts[nt * 16 + lm][h8 + 32];
      O[nt] = __builtin_amdgcn_mfma_f32_16x16x32_bf16(ap0, v0, O[nt], 0, 0, 0);
      O[nt] = __builtin_amdgcn_mfma_f32_16x16x32_bf16(ap1, v1, O[nt], 0, 0, 0);
    }
    __syncthreads();  // before next tile overwrites Ks/Vts
  }

  // epilogue: normalize, store ctx bf16 [b*S+s][h*64+dk]
  float inv[4];
  #pragma unroll
  for (int r = 0; r < 4; ++r) inv[r] = 1.f / l_[r];
  const int b = bh >> 4, h = bh & 15;
  #pragma unroll
  for (int nt = 0; nt < 4; ++nt) {
    int d = h * DK_ + nt * 16 + lm;
    #pragma unroll
    for (int r = 0; r < 4; ++r) {
      int s = i0 + w16 + q4 + r;
      ctx[((size_t)(b * S_ + s)) * D_ + d] = f2b(O[nt][r] * inv[r]);
    }
  }
}

// ---------------------------------------------------------------------------
extern "C" void kernel_launch(void* const* d_in, const int* in_sizes, int n_in,
                              void* d_out, int out_size, void* d_ws, size_t ws_size,
                              hipStream_t stream) {
  const float* q_in = (const float*)d_in[0];
  const float* k_in = (const float*)d_in[1];
  const float* v_in = (const float*)d_in[2];
  const float* Wq = (const float*)d_in[3];
  const float* bq = (const float*)d_in[4];
  const float* Wk = (const float*)d_in[5];
  const float* bk = (const float*)d_in[6];
  const float* Wv = (const float*)d_in[7];
  const float* bv = (const float*)d_in[8];
  const float* Wo = (const float*)d_in[9];
  const float* bo = (const float*)d_in[10];

  const size_t NE = (size_t)B_ * S_ * D_;  // 4,194,304
  ushort* Xbq = (ushort*)d_ws;
  ushort* Xbk = Xbq + NE;
  ushort* Xbv = Xbk + NE;
  ushort* Wtqkv = Xbv + NE;            // 3 * 1M rows-major [3072][1024]
  ushort* Wto = Wtqkv + 3 * 1024 * 1024;
  ushort* qfb = Wto + 1024 * 1024;     // [bh][s][dk]
  ushort* kfb = qfb + NE;
  ushort* vtb = kfb + NE;              // [bh][dk][s]
  ushort* ctxb = vtb + NE;             // [B*S][D]
  // total: 64 MB

  conv_x<<<2048, 256, 0, stream>>>(q_in, Xbq);
  conv_x<<<2048, 256, 0, stream>>>(k_in, Xbk);
  conv_x<<<2048, 256, 0, stream>>>(v_in, Xbv);
  transpose_w<<<dim3(16, 16), 256, 0, stream>>>(Wq, Wtqkv);
  transpose_w<<<dim3(16, 16), 256, 0, stream>>>(Wk, Wtqkv + 1024 * 1024);
  transpose_w<<<dim3(16, 16), 256, 0, stream>>>(Wv, Wtqkv + 2 * 1024 * 1024);
  transpose_w<<<dim3(16, 16), 256, 0, stream>>>(Wo, Wto);

  gemm_mfma<128, 0><<<dim3(32, 24), 256, 0, stream>>>(
      Xbq, Xbk, Xbv, Wtqkv, bq, bk, bv, qfb, kfb, vtb, nullptr);

  attn_mfma<<<dim3(32, 32), 256, 0, stream>>>(qfb, kfb, vtb, ctxb);

  gemm_mfma<64, 2><<<dim3(32, 16), 256, 0, stream>>>(
      ctxb, ctxb, ctxb, Wto, bo, bo, bo, nullptr, nullptr, nullptr,
      (float*)d_out);
}

// Round 5
// 470.135 us; speedup vs baseline: 3.9282x; 1.0025x over previous
//
#include <hip/hip_runtime.h>
#include <hip/hip_bf16.h>
#include <math.h>

// (B,S,D,H) = (2,2048,1024,16), DK=64
#define B_ 2
#define S_ 2048
#define D_ 1024
#define H_ 16
#define DK_ 64

#define ROPE_C 0.4152410118609203f   // log2(10000)/32
#define LOG2E 1.4426950408889634f

typedef float f4 __attribute__((ext_vector_type(4)));
typedef short s8 __attribute__((ext_vector_type(8)));

__device__ __forceinline__ ushort f2b(float f) {
  union { float f; uint u; } v; v.f = f;
  uint u = v.u + 0x7fffu + ((v.u >> 16) & 1u);
  return (ushort)(u >> 16);
}

// ---------------------------------------------------------------------------
// Prep 1: fp32 -> bf16 flat convert (4M elems). 8 elems/thread.
// ---------------------------------------------------------------------------
__global__ __launch_bounds__(256) void conv_x(const float* __restrict__ in,
                                              ushort* __restrict__ out) {
  int idx = (blockIdx.x * 256 + threadIdx.x) * 8;
  float4 a = *(const float4*)&in[idx];
  float4 b = *(const float4*)&in[idx + 4];
  ushort tmp[8] = {f2b(a.x), f2b(a.y), f2b(a.z), f2b(a.w),
                   f2b(b.x), f2b(b.y), f2b(b.z), f2b(b.w)};
  *(uint4*)&out[idx] = *(uint4*)tmp;
}

// ---------------------------------------------------------------------------
// Prep 2: W fp32 [K=1024][N=1024] -> Wt bf16 [N][K]. 64x64 LDS tiles.
// ---------------------------------------------------------------------------
__global__ __launch_bounds__(256) void transpose_w(const float* __restrict__ W,
                                                   ushort* __restrict__ Wt) {
  __shared__ ushort T[64][65];
  const int t = threadIdx.x;
  const int k0 = blockIdx.x * 64, n0 = blockIdx.y * 64;
  #pragma unroll
  for (int i = 0; i < 16; ++i) {
    int e = t + i * 256, r = e >> 6, c = e & 63;
    T[c][r] = f2b(W[(size_t)(k0 + r) * D_ + n0 + c]);
  }
  __syncthreads();
  #pragma unroll
  for (int i = 0; i < 16; ++i) {
    int e = t + i * 256, r = e >> 6, c = e & 63;
    Wt[(size_t)(n0 + r) * D_ + k0 + c] = T[r][c];
  }
}

// ---------------------------------------------------------------------------
// MFMA GEMM: C[M=4096][n] = A[m][k=1024] (bf16) @ Wt[n][k] (bf16) + bias.
// BM=128, BN template, BK=32, 256 thr = 4 waves (2x2), wave = 64 x BN/2.
// MODE 0: fused QKV epilogue (RoPE for Q/K, V transposed store), N=3072.
//         Epilogue staged through LDS -> dwordx4 coalesced stores.
// MODE 2: fp32 [M][N] + bias (final projection), direct stores.
// ---------------------------------------------------------------------------
template <int BN, int MODE>
__global__ __launch_bounds__(256) void gemm_mfma(
    const ushort* __restrict__ A0, const ushort* __restrict__ A1,
    const ushort* __restrict__ A2, const ushort* __restrict__ Bt,
    const float* __restrict__ bb0, const float* __restrict__ bb1,
    const float* __restrict__ bb2,
    ushort* __restrict__ oq, ushort* __restrict__ ok, ushort* __restrict__ ov,
    float* __restrict__ oo) {
  constexpr int NT = BN / 32;  // n-tiles per wave
  __shared__ ushort As[128][40];
  __shared__ ushort Bs[BN][40];
  // Epilogue scratch (MODE 0 only): viewed [64][144] for Q/K, [128][72] for V.
  __shared__ ushort Es[(MODE == 0) ? 9216 : 1];

  const int t = threadIdx.x, w = t >> 6, l = t & 63;
  const int m0 = blockIdx.x * 128, n0 = blockIdx.y * BN;
  const int wm = (w >> 1) * 64, wn = (w & 1) * (BN / 2);
  const int lm = l & 15, h8 = (l >> 4) * 8, q4 = (l >> 4) * 4;

  const ushort* A;
  const float* bias;
  int mat = 0;
  if constexpr (MODE == 0) {
    mat = n0 >> 10;
    A = (mat == 0) ? A0 : (mat == 1) ? A1 : A2;
    bias = (mat == 0) ? bb0 : (mat == 1) ? bb1 : bb2;
  } else {
    A = A0; bias = bb0;
  }

  f4 acc[4][NT];
  #pragma unroll
  for (int i = 0; i < 4; ++i)
    #pragma unroll
    for (int j = 0; j < NT; ++j) acc[i][j] = (f4){0.f, 0.f, 0.f, 0.f};

  for (int k0 = 0; k0 < D_; k0 += 32) {
    #pragma unroll
    for (int i = 0; i < 2; ++i) {
      int g = t + i * 256, r = g >> 2, c = (g & 3) * 8;
      *(uint4*)&As[r][c] = *(const uint4*)&A[(size_t)(m0 + r) * D_ + k0 + c];
    }
    #pragma unroll
    for (int i = 0; i < BN / 64; ++i) {
      int g = t + i * 256, r = g >> 2, c = (g & 3) * 8;
      *(uint4*)&Bs[r][c] = *(const uint4*)&Bt[(size_t)(n0 + r) * D_ + k0 + c];
    }
    __syncthreads();
    s8 af[4], bfr[NT];
    #pragma unroll
    for (int mt = 0; mt < 4; ++mt) af[mt] = *(const s8*)&As[wm + mt * 16 + lm][h8];
    #pragma unroll
    for (int nt = 0; nt < NT; ++nt) bfr[nt] = *(const s8*)&Bs[wn + nt * 16 + lm][h8];
    #pragma unroll
    for (int mt = 0; mt < 4; ++mt)
      #pragma unroll
      for (int nt = 0; nt < NT; ++nt)
        acc[mt][nt] = __builtin_amdgcn_mfma_f32_16x16x32_bf16(af[mt], bfr[nt], acc[mt][nt], 0, 0, 0);
    __syncthreads();
  }

  // ---- epilogue ----
  if constexpr (MODE == 2) {
    #pragma unroll
    for (int nt = 0; nt < NT; ++nt) {
      int n = n0 + wn + nt * 16 + lm;
      float bv = bias[n];
      #pragma unroll
      for (int mt = 0; mt < 4; ++mt)
        #pragma unroll
        for (int r = 0; r < 4; ++r)
          oo[(size_t)(m0 + wm + mt * 16 + q4 + r) * D_ + n] = acc[mt][nt][r] + bv;
    }
  } else {
    const int hbase = (n0 & 1023) >> 6;  // first of the 2 heads this block covers
    const int bb = m0 >> 11;             // batch index (m0 aligned within batch)
    if (mat < 2) {
      // -------- Q/K: RoPE in-register, stage [s][128 cols] in LDS, 16B stores
      ushort* dst = (mat == 0) ? oq : ok;
      const float scale = (mat == 0) ? 0.125f : 1.f;
      #pragma unroll
      for (int p = 0; p < 2; ++p) {
        if ((w >> 1) == p) {
          #pragma unroll
          for (int nt = 0; nt < NT; ++nt) {
            int col = wn + nt * 16 + lm;  // 0..127
            int dk = col & 63;
            float bv = bias[(n0 & 1023) + col];
            float invf_s = exp2f(-(float)(dk & 31) * ROPE_C);
            float invf_p = exp2f(-(float)((dk ^ 1) & 31) * ROPE_C);
            float sgn = (dk & 1) ? 1.f : -1.f;
            #pragma unroll
            for (int mt = 0; mt < 4; ++mt) {
              #pragma unroll
              for (int r = 0; r < 4; ++r) {
                int mloc = mt * 16 + q4 + r;  // 0..63
                int m = m0 + p * 64 + mloc;
                float x = acc[mt][nt][r] + bv;
                float px = __shfl_xor(x, 1);
                float pos = (float)(m & (S_ - 1));
                float cs = cosf(pos * invf_s), sp = sinf(pos * invf_p);
                Es[mloc * 144 + col] = f2b((x * cs + sgn * px * sp) * scale);
              }
            }
          }
        }
        __syncthreads();
        #pragma unroll
        for (int i = 0; i < 4; ++i) {
          int e = t + i * 256;
          int row = e >> 4, ch = e & 15;  // 16 chunks of 16B per 256B row
          int m = m0 + p * 64 + row;
          int sr = m & (S_ - 1);
          int h = hbase + (ch >> 3);
          int dkb = (ch & 7) * 8;
          *(uint4*)&dst[((size_t)(bb * H_ + h) * S_ + sr) * DK_ + dkb] =
              *(const uint4*)&Es[row * 144 + ch * 8];
        }
        __syncthreads();
      }
    } else {
      // -------- V: stage transposed [n][s] in LDS, 16B stores to [bh][dk][S]
      #pragma unroll
      for (int p = 0; p < 2; ++p) {
        if ((w >> 1) == p) {
          #pragma unroll
          for (int nt = 0; nt < NT; ++nt) {
            int col = wn + nt * 16 + lm;
            float bv = bias[(n0 & 1023) + col];
            #pragma unroll
            for (int mt = 0; mt < 4; ++mt)
              #pragma unroll
              for (int r = 0; r < 4; ++r)
                Es[col * 72 + mt * 16 + q4 + r] = f2b(acc[mt][nt][r] + bv);
          }
        }
        __syncthreads();
        int sr0 = m0 + p * 64;
        int srr = sr0 & (S_ - 1);
        #pragma unroll
        for (int i = 0; i < 4; ++i) {
          int e = t + i * 256;
          int row = e >> 3, ch = e & 7;  // row = col index 0..127
          int h = hbase + (row >> 6), dk = row & 63;
          *(uint4*)&ov[((size_t)(bb * H_ + h) * DK_ + dk) * S_ + srr + ch * 8] =
              *(const uint4*)&Es[row * 72 + ch * 8];
        }
        __syncthreads();
      }
    }
  }
}

// ---------------------------------------------------------------------------
// MFMA flash attention. Grid (32 bh, 32 qt), 256 thr = 4 waves x 16 Q-rows.
// Q pre-scaled. qf/kf: [bh][s][64] bf16; vtf: [bh][dk][2048] bf16.
// ctx out bf16 [B*S][1024], staged through Qs for coalesced 16B stores.
// ---------------------------------------------------------------------------
__global__ __launch_bounds__(256) void attn_mfma(const ushort* __restrict__ qf,
                                                 const ushort* __restrict__ kf,
                                                 const ushort* __restrict__ vtf,
                                                 ushort* __restrict__ ctx) {
  __shared__ ushort Qs[64][72], Ks[64][72], Vts[64][72], Ps[64][72];

  const int t = threadIdx.x, w = t >> 6, l = t & 63;
  const int bh = blockIdx.x, qt = blockIdx.y;
  const int i0 = qt * 64;
  const int lm = l & 15, h8 = (l >> 4) * 8, q4 = (l >> 4) * 4, w16 = w * 16;
  const size_t base = (size_t)bh * S_ * DK_;

  #pragma unroll
  for (int i = 0; i < 2; ++i) {
    int g = t + i * 256, r = g >> 3, c = (g & 7) * 8;
    *(uint4*)&Qs[r][c] = *(const uint4*)&qf[base + (size_t)(i0 + r) * DK_ + c];
  }

  f4 O[4];
  #pragma unroll
  for (int i = 0; i < 4; ++i) O[i] = (f4){0.f, 0.f, 0.f, 0.f};
  float m_[4] = {-1e30f, -1e30f, -1e30f, -1e30f};
  float l_[4] = {0.f, 0.f, 0.f, 0.f};

  for (int jt = 0; jt <= qt; ++jt) {
    const int j0 = jt * 64;
    #pragma unroll
    for (int i = 0; i < 2; ++i) {
      int g = t + i * 256, r = g >> 3, c = (g & 7) * 8;
      *(uint4*)&Ks[r][c] = *(const uint4*)&kf[base + (size_t)(j0 + r) * DK_ + c];
      *(uint4*)&Vts[r][c] = *(const uint4*)&vtf[base + (size_t)r * S_ + j0 + c];
    }
    __syncthreads();  // covers Q staging on first iter

    // QK^T
    s8 aq0 = *(const s8*)&Qs[w16 + lm][h8];
    s8 aq1 = *(const s8*)&Qs[w16 + lm][h8 + 32];
    f4 sc[4];
    #pragma unroll
    for (int nt = 0; nt < 4; ++nt) {
      s8 b0 = *(const s8*)&Ks[nt * 16 + lm][h8];
      s8 b1 = *(const s8*)&Ks[nt * 16 + lm][h8 + 32];
      f4 a = (f4){0.f, 0.f, 0.f, 0.f};
      a = __builtin_amdgcn_mfma_f32_16x16x32_bf16(aq0, b0, a, 0, 0, 0);
      a = __builtin_amdgcn_mfma_f32_16x16x32_bf16(aq1, b1, a, 0, 0, 0);
      sc[nt] = a;
    }
    if (jt == qt) {  // causal mask on diagonal tile
      #pragma unroll
      for (int nt = 0; nt < 4; ++nt)
        #pragma unroll
        for (int r = 0; r < 4; ++r)
          if (nt * 16 + lm > w16 + q4 + r) sc[nt][r] = -1e30f;
    }
    // online softmax (rows owned by 16-lane groups)
    float rmax[4];
    #pragma unroll
    for (int r = 0; r < 4; ++r)
      rmax[r] = fmaxf(fmaxf(sc[0][r], sc[1][r]), fmaxf(sc[2][r], sc[3][r]));
    #pragma unroll
    for (int off = 1; off < 16; off <<= 1)
      #pragma unroll
      for (int r = 0; r < 4; ++r) rmax[r] = fmaxf(rmax[r], __shfl_xor(rmax[r], off));
    float alpha[4];
    #pragma unroll
    for (int r = 0; r < 4; ++r) {
      float mn = fmaxf(m_[r], rmax[r]);
      alpha[r] = exp2f((m_[r] - mn) * LOG2E);
      m_[r] = mn;
    }
    float rsum[4] = {0.f, 0.f, 0.f, 0.f};
    #pragma unroll
    for (int nt = 0; nt < 4; ++nt)
      #pragma unroll
      for (int r = 0; r < 4; ++r) {
        float p = exp2f((sc[nt][r] - m_[r]) * LOG2E);
        sc[nt][r] = p;
        rsum[r] += p;
      }
    #pragma unroll
    for (int off = 1; off < 16; off <<= 1)
      #pragma unroll
      for (int r = 0; r < 4; ++r) rsum[r] += __shfl_xor(rsum[r], off);
    #pragma unroll
    for (int r = 0; r < 4; ++r) l_[r] = l_[r] * alpha[r] + rsum[r];
    // P -> LDS (A-layout round trip), per-wave region
    #pragma unroll
    for (int nt = 0; nt < 4; ++nt)
      #pragma unroll
      for (int r = 0; r < 4; ++r)
        Ps[w16 + q4 + r][nt * 16 + lm] = f2b(sc[nt][r]);
    #pragma unroll
    for (int nt = 0; nt < 4; ++nt)
      #pragma unroll
      for (int r = 0; r < 4; ++r) O[nt][r] *= alpha[r];
    // PV
    s8 ap0 = *(const s8*)&Ps[w16 + lm][h8];
    s8 ap1 = *(const s8*)&Ps[w16 + lm][h8 + 32];
    #pragma unroll
    for (int nt = 0; nt < 4; ++nt) {
      s8 v0 = *(const s8*)&Vts[nt * 16 + lm][h8];
      s8 v1 = *(const s8*)&Vts[nt * 16 + lm][h8 + 32];
      O[nt] = __builtin_amdgcn_mfma_f32_16x16x32_bf16(ap0, v0, O[nt], 0, 0, 0);
      O[nt] = __builtin_amdgcn_mfma_f32_16x16x32_bf16(ap1, v1, O[nt], 0, 0, 0);
    }
    __syncthreads();  // before next tile overwrites Ks/Vts
  }

  // epilogue: normalize, stage in Qs (dead after loop), coalesced 16B stores
  float inv[4];
  #pragma unroll
  for (int r = 0; r < 4; ++r) inv[r] = 1.f / l_[r];
  #pragma unroll
  for (int nt = 0; nt < 4; ++nt)
    #pragma unroll
    for (int r = 0; r < 4; ++r)
      Qs[w16 + q4 + r][nt * 16 + lm] = f2b(O[nt][r] * inv[r]);
  __syncthreads();
  const int b = bh >> 4, h = bh & 15;
  #pragma unroll
  for (int i = 0; i < 2; ++i) {
    int e = t + i * 256;
    int row = e >> 3, ch = e & 7;  // 8 chunks of 16B per 128B row
    int s = i0 + row;
    *(uint4*)&ctx[((size_t)(b * S_ + s)) * D_ + h * 64 + ch * 8] =
        *(const uint4*)&Qs[row][ch * 8];
  }
}

// ---------------------------------------------------------------------------
extern "C" void kernel_launch(void* const* d_in, const int* in_sizes, int n_in,
                              void* d_out, int out_size, void* d_ws, size_t ws_size,
                              hipStream_t stream) {
  const float* q_in = (const float*)d_in[0];
  const float* k_in = (const float*)d_in[1];
  const float* v_in = (const float*)d_in[2];
  const float* Wq = (const float*)d_in[3];
  const float* bq = (const float*)d_in[4];
  const float* Wk = (const float*)d_in[5];
  const float* bk = (const float*)d_in[6];
  const float* Wv = (const float*)d_in[7];
  const float* bv = (const float*)d_in[8];
  const float* Wo = (const float*)d_in[9];
  const float* bo = (const float*)d_in[10];

  const size_t NE = (size_t)B_ * S_ * D_;  // 4,194,304
  ushort* Xbq = (ushort*)d_ws;
  ushort* Xbk = Xbq + NE;
  ushort* Xbv = Xbk + NE;
  ushort* Wtqkv = Xbv + NE;            // [3072][1024] bf16
  ushort* Wto = Wtqkv + 3 * 1024 * 1024;
  ushort* qfb = Wto + 1024 * 1024;     // [bh][s][dk]
  ushort* kfb = qfb + NE;
  ushort* vtb = kfb + NE;              // [bh][dk][s]
  ushort* ctxb = vtb + NE;             // [B*S][D]

  conv_x<<<2048, 256, 0, stream>>>(q_in, Xbq);
  conv_x<<<2048, 256, 0, stream>>>(k_in, Xbk);
  conv_x<<<2048, 256, 0, stream>>>(v_in, Xbv);
  transpose_w<<<dim3(16, 16), 256, 0, stream>>>(Wq, Wtqkv);
  transpose_w<<<dim3(16, 16), 256, 0, stream>>>(Wk, Wtqkv + 1024 * 1024);
  transpose_w<<<dim3(16, 16), 256, 0, stream>>>(Wv, Wtqkv + 2 * 1024 * 1024);
  transpose_w<<<dim3(16, 16), 256, 0, stream>>>(Wo, Wto);

  gemm_mfma<128, 0><<<dim3(32, 24), 256, 0, stream>>>(
      Xbq, Xbk, Xbv, Wtqkv, bq, bk, bv, qfb, kfb, vtb, nullptr);

  attn_mfma<<<dim3(32, 32), 256, 0, stream>>>(qfb, kfb, vtb, ctxb);

  gemm_mfma<64, 2><<<dim3(32, 16), 256, 0, stream>>>(
      ctxb, ctxb, ctxb, Wto, bo, bo, bo, nullptr, nullptr, nullptr,
      (float*)d_out);
}

// Round 6
// 469.964 us; speedup vs baseline: 3.9296x; 1.0004x over previous
//
#include <hip/hip_runtime.h>
#include <hip/hip_bf16.h>
#include <math.h>

// (B,S,D,H) = (2,2048,1024,16), DK=64
#define B_ 2
#define S_ 2048
#define D_ 1024
#define H_ 16
#define DK_ 64

#define ROPE_C 0.4152410118609203f   // log2(10000)/32
#define LOG2E 1.4426950408889634f

typedef float f4 __attribute__((ext_vector_type(4)));
typedef short s8 __attribute__((ext_vector_type(8)));

__device__ __forceinline__ ushort f2b(float f) {
  union { float f; uint u; } v; v.f = f;
  uint u = v.u + 0x7fffu + ((v.u >> 16) & 1u);
  return (ushort)(u >> 16);
}

// async global->LDS DMA, 16 B per lane. LDS dest = wave-uniform base + lane*16.
__device__ __forceinline__ void async16(const ushort* g, ushort* l) {
  __builtin_amdgcn_global_load_lds(
      (const __attribute__((address_space(1))) uint*)g,
      (__attribute__((address_space(3))) uint*)l, 16, 0, 0);
}

// ---------------------------------------------------------------------------
// Prep 1: fp32 -> bf16 flat convert (4M elems). 8 elems/thread.
// ---------------------------------------------------------------------------
__global__ __launch_bounds__(256) void conv_x(const float* __restrict__ in,
                                              ushort* __restrict__ out) {
  int idx = (blockIdx.x * 256 + threadIdx.x) * 8;
  float4 a = *(const float4*)&in[idx];
  float4 b = *(const float4*)&in[idx + 4];
  ushort tmp[8] = {f2b(a.x), f2b(a.y), f2b(a.z), f2b(a.w),
                   f2b(b.x), f2b(b.y), f2b(b.z), f2b(b.w)};
  *(uint4*)&out[idx] = *(uint4*)tmp;
}

// ---------------------------------------------------------------------------
// Prep 2: W fp32 [K=1024][N=1024] -> Wt bf16 [N][K]. 64x64 LDS tiles.
// ---------------------------------------------------------------------------
__global__ __launch_bounds__(256) void transpose_w(const float* __restrict__ W,
                                                   ushort* __restrict__ Wt) {
  __shared__ ushort T[64][65];
  const int t = threadIdx.x;
  const int k0 = blockIdx.x * 64, n0 = blockIdx.y * 64;
  #pragma unroll
  for (int i = 0; i < 16; ++i) {
    int e = t + i * 256, r = e >> 6, c = e & 63;
    T[c][r] = f2b(W[(size_t)(k0 + r) * D_ + n0 + c]);
  }
  __syncthreads();
  #pragma unroll
  for (int i = 0; i < 16; ++i) {
    int e = t + i * 256, r = e >> 6, c = e & 63;
    Wt[(size_t)(n0 + r) * D_ + k0 + c] = T[r][c];
  }
}

// ---------------------------------------------------------------------------
// MFMA GEMM, m97-style K-loop: BM=BN=128, BK=32, 4 waves 2x2, 4x4 frags/wave.
// Staging: global_load_lds width-16 into unpadded [128][32] LDS tiles with
// XOR-block swizzle: physical 16B-block = logical_block ^ (row & 3).
// MODE 0: fused QKV epilogue via LDS (RoPE Q/K, V transposed), N=3072.
// MODE 2: fp32 [M][N] + bias (final projection), direct stores.
// ---------------------------------------------------------------------------
template <int MODE>
__global__ __launch_bounds__(256) void gemm_mfma(
    const ushort* __restrict__ A0, const ushort* __restrict__ A1,
    const ushort* __restrict__ A2, const ushort* __restrict__ Bt,
    const float* __restrict__ bb0, const float* __restrict__ bb1,
    const float* __restrict__ bb2,
    ushort* __restrict__ oq, ushort* __restrict__ ok, ushort* __restrict__ ov,
    float* __restrict__ oo) {
  __shared__ ushort As[128 * 32];
  __shared__ ushort Bs[128 * 32];
  __shared__ ushort Es[(MODE == 0) ? 9216 : 1];  // epilogue scratch (MODE 0)

  const int t = threadIdx.x, w = t >> 6, l = t & 63;
  const int m0 = blockIdx.x * 128, n0 = blockIdx.y * 128;
  const int wm = (w >> 1) * 64, wn = (w & 1) * 64;
  const int lm = l & 15, h8 = (l >> 4) * 8, q4 = (l >> 4) * 4;
  const int hb = l >> 4;  // logical 16B block 0..3 of the K dim

  const ushort* A;
  const float* bias;
  int mat = 0;
  if constexpr (MODE == 0) {
    mat = n0 >> 10;
    A = (mat == 0) ? A0 : (mat == 1) ? A1 : A2;
    bias = (mat == 0) ? bb0 : (mat == 1) ? bb1 : bb2;
  } else {
    A = A0; bias = bb0;
  }

  // Staging geometry: lane l, call i in {0,1}: row = w*32 + i*16 + (l>>2),
  // physical block pb = l&3 -> stage global logical block pb ^ (row&3).
  const int srow = w * 32 + (l >> 2);
  const int pb = l & 3;
  const int lb = pb ^ (srow & 3);  // (srow+16)&3 == srow&3
  const ushort* gA = A + (size_t)(m0 + srow) * D_ + lb * 8;
  const ushort* gB = Bt + (size_t)(n0 + srow) * D_ + lb * 8;
  ushort* lA = As + w * 1024;  // wave-uniform base; +512 elems for call 2
  ushort* lB = Bs + w * 1024;

  f4 acc[4][4];
  #pragma unroll
  for (int i = 0; i < 4; ++i)
    #pragma unroll
    for (int j = 0; j < 4; ++j) acc[i][j] = (f4){0.f, 0.f, 0.f, 0.f};

  for (int k0 = 0; k0 < D_; k0 += 32) {
    async16(gA + k0, lA);
    async16(gA + 16 * D_ + k0, lA + 512);
    async16(gB + k0, lB);
    async16(gB + 16 * D_ + k0, lB + 512);
    __syncthreads();  // drains vmcnt, publishes LDS
    s8 af[4], bfr[4];
    #pragma unroll
    for (int mt = 0; mt < 4; ++mt) {
      int ra = wm + mt * 16 + lm;
      af[mt] = *(const s8*)&As[ra * 32 + ((hb ^ (ra & 3)) << 3)];
    }
    #pragma unroll
    for (int nt = 0; nt < 4; ++nt) {
      int rb = wn + nt * 16 + lm;
      bfr[nt] = *(const s8*)&Bs[rb * 32 + ((hb ^ (rb & 3)) << 3)];
    }
    #pragma unroll
    for (int mt = 0; mt < 4; ++mt)
      #pragma unroll
      for (int nt = 0; nt < 4; ++nt)
        acc[mt][nt] = __builtin_amdgcn_mfma_f32_16x16x32_bf16(af[mt], bfr[nt], acc[mt][nt], 0, 0, 0);
    __syncthreads();
  }

  // ---- epilogue ----
  if constexpr (MODE == 2) {
    #pragma unroll
    for (int nt = 0; nt < 4; ++nt) {
      int n = n0 + wn + nt * 16 + lm;
      float bv = bias[n];
      #pragma unroll
      for (int mt = 0; mt < 4; ++mt)
        #pragma unroll
        for (int r = 0; r < 4; ++r)
          oo[(size_t)(m0 + wm + mt * 16 + q4 + r) * D_ + n] = acc[mt][nt][r] + bv;
    }
  } else {
    const int hbase = (n0 & 1023) >> 6;  // first of the 2 heads this block covers
    const int bb = m0 >> 11;             // batch index
    if (mat < 2) {
      // Q/K: RoPE in-register, stage [s][128] in LDS (stride 144), 16B stores
      ushort* dst = (mat == 0) ? oq : ok;
      const float scale = (mat == 0) ? 0.125f : 1.f;
      #pragma unroll
      for (int p = 0; p < 2; ++p) {
        if ((w >> 1) == p) {
          #pragma unroll
          for (int nt = 0; nt < 4; ++nt) {
            int col = wn + nt * 16 + lm;  // 0..127
            int dk = col & 63;
            float bv = bias[(n0 & 1023) + col];
            float invf_s = exp2f(-(float)(dk & 31) * ROPE_C);
            float invf_p = exp2f(-(float)((dk ^ 1) & 31) * ROPE_C);
            float sgn = (dk & 1) ? 1.f : -1.f;
            #pragma unroll
            for (int mt = 0; mt < 4; ++mt) {
              #pragma unroll
              for (int r = 0; r < 4; ++r) {
                int mloc = mt * 16 + q4 + r;  // 0..63
                int m = m0 + p * 64 + mloc;
                float x = acc[mt][nt][r] + bv;
                float px = __shfl_xor(x, 1);
                float pos = (float)(m & (S_ - 1));
                float cs = cosf(pos * invf_s), sp = sinf(pos * invf_p);
                Es[mloc * 144 + col] = f2b((x * cs + sgn * px * sp) * scale);
              }
            }
          }
        }
        __syncthreads();
        #pragma unroll
        for (int i = 0; i < 4; ++i) {
          int e = t + i * 256;
          int row = e >> 4, ch = e & 15;  // 16 chunks of 16B per 256B row
          int m = m0 + p * 64 + row;
          int sr = m & (S_ - 1);
          int h = hbase + (ch >> 3);
          int dkb = (ch & 7) * 8;
          *(uint4*)&dst[((size_t)(bb * H_ + h) * S_ + sr) * DK_ + dkb] =
              *(const uint4*)&Es[row * 144 + ch * 8];
        }
        __syncthreads();
      }
    } else {
      // V: stage transposed [n][s] in LDS (stride 72), 16B stores to [bh][dk][S]
      #pragma unroll
      for (int p = 0; p < 2; ++p) {
        if ((w >> 1) == p) {
          #pragma unroll
          for (int nt = 0; nt < 4; ++nt) {
            int col = wn + nt * 16 + lm;
            float bv = bias[(n0 & 1023) + col];
            #pragma unroll
            for (int mt = 0; mt < 4; ++mt)
              #pragma unroll
              for (int r = 0; r < 4; ++r)
                Es[col * 72 + mt * 16 + q4 + r] = f2b(acc[mt][nt][r] + bv);
          }
        }
        __syncthreads();
        int srr = (m0 + p * 64) & (S_ - 1);
        #pragma unroll
        for (int i = 0; i < 4; ++i) {
          int e = t + i * 256;
          int row = e >> 3, ch = e & 7;  // row = col index 0..127
          int h = hbase + (row >> 6), dk = row & 63;
          *(uint4*)&ov[((size_t)(bb * H_ + h) * DK_ + dk) * S_ + srr + ch * 8] =
              *(const uint4*)&Es[row * 72 + ch * 8];
        }
        __syncthreads();
      }
    }
  }
}

// ---------------------------------------------------------------------------
// MFMA flash attention. Grid (32 bh, 32 qt), 256 thr = 4 waves x 16 Q-rows.
// Q pre-scaled. qf/kf: [bh][s][64] bf16; vtf: [bh][dk][2048] bf16.
// ctx out bf16 [B*S][1024], staged through Qs for coalesced 16B stores.
// ---------------------------------------------------------------------------
__global__ __launch_bounds__(256) void attn_mfma(const ushort* __restrict__ qf,
                                                 const ushort* __restrict__ kf,
                                                 const ushort* __restrict__ vtf,
                                                 ushort* __restrict__ ctx) {
  __shared__ ushort Qs[64][72], Ks[64][72], Vts[64][72], Ps[64][72];

  const int t = threadIdx.x, w = t >> 6, l = t & 63;
  const int bh = blockIdx.x, qt = blockIdx.y;
  const int i0 = qt * 64;
  const int lm = l & 15, h8 = (l >> 4) * 8, q4 = (l >> 4) * 4, w16 = w * 16;
  const size_t base = (size_t)bh * S_ * DK_;

  #pragma unroll
  for (int i = 0; i < 2; ++i) {
    int g = t + i * 256, r = g >> 3, c = (g & 7) * 8;
    *(uint4*)&Qs[r][c] = *(const uint4*)&qf[base + (size_t)(i0 + r) * DK_ + c];
  }

  f4 O[4];
  #pragma unroll
  for (int i = 0; i < 4; ++i) O[i] = (f4){0.f, 0.f, 0.f, 0.f};
  float m_[4] = {-1e30f, -1e30f, -1e30f, -1e30f};
  float l_[4] = {0.f, 0.f, 0.f, 0.f};

  for (int jt = 0; jt <= qt; ++jt) {
    const int j0 = jt * 64;
    #pragma unroll
    for (int i = 0; i < 2; ++i) {
      int g = t + i * 256, r = g >> 3, c = (g & 7) * 8;
      *(uint4*)&Ks[r][c] = *(const uint4*)&kf[base + (size_t)(j0 + r) * DK_ + c];
      *(uint4*)&Vts[r][c] = *(const uint4*)&vtf[base + (size_t)r * S_ + j0 + c];
    }
    __syncthreads();  // covers Q staging on first iter

    // QK^T
    s8 aq0 = *(const s8*)&Qs[w16 + lm][h8];
    s8 aq1 = *(const s8*)&Qs[w16 + lm][h8 + 32];
    f4 sc[4];
    #pragma unroll
    for (int nt = 0; nt < 4; ++nt) {
      s8 b0 = *(const s8*)&Ks[nt * 16 + lm][h8];
      s8 b1 = *(const s8*)&Ks[nt * 16 + lm][h8 + 32];
      f4 a = (f4){0.f, 0.f, 0.f, 0.f};
      a = __builtin_amdgcn_mfma_f32_16x16x32_bf16(aq0, b0, a, 0, 0, 0);
      a = __builtin_amdgcn_mfma_f32_16x16x32_bf16(aq1, b1, a, 0, 0, 0);
      sc[nt] = a;
    }
    if (jt == qt) {  // causal mask on diagonal tile
      #pragma unroll
      for (int nt = 0; nt < 4; ++nt)
        #pragma unroll
        for (int r = 0; r < 4; ++r)
          if (nt * 16 + lm > w16 + q4 + r) sc[nt][r] = -1e30f;
    }
    // online softmax (rows owned by 16-lane groups)
    float rmax[4];
    #pragma unroll
    for (int r = 0; r < 4; ++r)
      rmax[r] = fmaxf(fmaxf(sc[0][r], sc[1][r]), fmaxf(sc[2][r], sc[3][r]));
    #pragma unroll
    for (int off = 1; off < 16; off <<= 1)
      #pragma unroll
      for (int r = 0; r < 4; ++r) rmax[r] = fmaxf(rmax[r], __shfl_xor(rmax[r], off));
    float alpha[4];
    #pragma unroll
    for (int r = 0; r < 4; ++r) {
      float mn = fmaxf(m_[r], rmax[r]);
      alpha[r] = exp2f((m_[r] - mn) * LOG2E);
      m_[r] = mn;
    }
    float rsum[4] = {0.f, 0.f, 0.f, 0.f};
    #pragma unroll
    for (int nt = 0; nt < 4; ++nt)
      #pragma unroll
      for (int r = 0; r < 4; ++r) {
        float p = exp2f((sc[nt][r] - m_[r]) * LOG2E);
        sc[nt][r] = p;
        rsum[r] += p;
      }
    #pragma unroll
    for (int off = 1; off < 16; off <<= 1)
      #pragma unroll
      for (int r = 0; r < 4; ++r) rsum[r] += __shfl_xor(rsum[r], off);
    #pragma unroll
    for (int r = 0; r < 4; ++r) l_[r] = l_[r] * alpha[r] + rsum[r];
    // P -> LDS (A-layout round trip), per-wave region
    #pragma unroll
    for (int nt = 0; nt < 4; ++nt)
      #pragma unroll
      for (int r = 0; r < 4; ++r)
        Ps[w16 + q4 + r][nt * 16 + lm] = f2b(sc[nt][r]);
    #pragma unroll
    for (int nt = 0; nt < 4; ++nt)
      #pragma unroll
      for (int r = 0; r < 4; ++r) O[nt][r] *= alpha[r];
    // PV
    s8 ap0 = *(const s8*)&Ps[w16 + lm][h8];
    s8 ap1 = *(const s8*)&Ps[w16 + lm][h8 + 32];
    #pragma unroll
    for (int nt = 0; nt < 4; ++nt) {
      s8 v0 = *(const s8*)&Vts[nt * 16 + lm][h8];
      s8 v1 = *(const s8*)&Vts[nt * 16 + lm][h8 + 32];
      O[nt] = __builtin_amdgcn_mfma_f32_16x16x32_bf16(ap0, v0, O[nt], 0, 0, 0);
      O[nt] = __builtin_amdgcn_mfma_f32_16x16x32_bf16(ap1, v1, O[nt], 0, 0, 0);
    }
    __syncthreads();  // before next tile overwrites Ks/Vts
  }

  // epilogue: normalize, stage in Qs (dead), coalesced 16B stores
  float inv[4];
  #pragma unroll
  for (int r = 0; r < 4; ++r) inv[r] = 1.f / l_[r];
  #pragma unroll
  for (int nt = 0; nt < 4; ++nt)
    #pragma unroll
    for (int r = 0; r < 4; ++r)
      Qs[w16 + q4 + r][nt * 16 + lm] = f2b(O[nt][r] * inv[r]);
  __syncthreads();
  const int b = bh >> 4, h = bh & 15;
  #pragma unroll
  for (int i = 0; i < 2; ++i) {
    int e = t + i * 256;
    int row = e >> 3, ch = e & 7;
    int s = i0 + row;
    *(uint4*)&ctx[((size_t)(b * S_ + s)) * D_ + h * 64 + ch * 8] =
        *(const uint4*)&Qs[row][ch * 8];
  }
}

// ---------------------------------------------------------------------------
extern "C" void kernel_launch(void* const* d_in, const int* in_sizes, int n_in,
                              void* d_out, int out_size, void* d_ws, size_t ws_size,
                              hipStream_t stream) {
  const float* q_in = (const float*)d_in[0];
  const float* k_in = (const float*)d_in[1];
  const float* v_in = (const float*)d_in[2];
  const float* Wq = (const float*)d_in[3];
  const float* bq = (const float*)d_in[4];
  const float* Wk = (const float*)d_in[5];
  const float* bk = (const float*)d_in[6];
  const float* Wv = (const float*)d_in[7];
  const float* bv = (const float*)d_in[8];
  const float* Wo = (const float*)d_in[9];
  const float* bo = (const float*)d_in[10];

  const size_t NE = (size_t)B_ * S_ * D_;  // 4,194,304
  ushort* Xbq = (ushort*)d_ws;
  ushort* Xbk = Xbq + NE;
  ushort* Xbv = Xbk + NE;
  ushort* Wtqkv = Xbv + NE;            // [3072][1024] bf16
  ushort* Wto = Wtqkv + 3 * 1024 * 1024;
  ushort* qfb = Wto + 1024 * 1024;     // [bh][s][dk]
  ushort* kfb = qfb + NE;
  ushort* vtb = kfb + NE;              // [bh][dk][s]
  ushort* ctxb = vtb + NE;             // [B*S][D]

  conv_x<<<2048, 256, 0, stream>>>(q_in, Xbq);
  conv_x<<<2048, 256, 0, stream>>>(k_in, Xbk);
  conv_x<<<2048, 256, 0, stream>>>(v_in, Xbv);
  transpose_w<<<dim3(16, 16), 256, 0, stream>>>(Wq, Wtqkv);
  transpose_w<<<dim3(16, 16), 256, 0, stream>>>(Wk, Wtqkv + 1024 * 1024);
  transpose_w<<<dim3(16, 16), 256, 0, stream>>>(Wv, Wtqkv + 2 * 1024 * 1024);
  transpose_w<<<dim3(16, 16), 256, 0, stream>>>(Wo, Wto);

  gemm_mfma<0><<<dim3(32, 24), 256, 0, stream>>>(
      Xbq, Xbk, Xbv, Wtqkv, bq, bk, bv, qfb, kfb, vtb, nullptr);

  attn_mfma<<<dim3(32, 32), 256, 0, stream>>>(qfb, kfb, vtb, ctxb);

  gemm_mfma<2><<<dim3(32, 8), 256, 0, stream>>>(
      ctxb, ctxb, ctxb, Wto, bo, bo, bo, nullptr, nullptr, nullptr,
      (float*)d_out);
}

// Round 7
// 303.042 us; speedup vs baseline: 6.0941x; 1.5508x over previous
//
#include <hip/hip_runtime.h>
#include <hip/hip_bf16.h>
#include <math.h>

// (B,S,D,H) = (2,2048,1024,16), DK=64
#define B_ 2
#define S_ 2048
#define D_ 1024
#define H_ 16
#define DK_ 64

#define ROPE_C 0.4152410118609203f   // log2(10000)/32
#define LOG2E 1.4426950408889634f

typedef float f4 __attribute__((ext_vector_type(4)));
typedef short s8 __attribute__((ext_vector_type(8)));

__device__ __forceinline__ ushort f2b(float f) {
  union { float f; uint u; } v; v.f = f;
  uint u = v.u + 0x7fffu + ((v.u >> 16) & 1u);
  return (ushort)(u >> 16);
}

__device__ __forceinline__ float b2f(ushort u) {
  union { uint u; float f; } v; v.u = ((uint)u) << 16;
  return v.f;
}

// async global->LDS DMA, 16 B per lane. LDS dest = wave-uniform base + lane*16.
__device__ __forceinline__ void async16(const ushort* g, ushort* l) {
  __builtin_amdgcn_global_load_lds(
      (const __attribute__((address_space(1))) uint*)g,
      (__attribute__((address_space(3))) uint*)l, 16, 0, 0);
}

// ---------------------------------------------------------------------------
// Prep 1: fp32 -> bf16 flat convert (4M elems). 8 elems/thread.
// ---------------------------------------------------------------------------
__global__ __launch_bounds__(256) void conv_x(const float* __restrict__ in,
                                              ushort* __restrict__ out) {
  int idx = (blockIdx.x * 256 + threadIdx.x) * 8;
  float4 a = *(const float4*)&in[idx];
  float4 b = *(const float4*)&in[idx + 4];
  ushort tmp[8] = {f2b(a.x), f2b(a.y), f2b(a.z), f2b(a.w),
                   f2b(b.x), f2b(b.y), f2b(b.z), f2b(b.w)};
  *(uint4*)&out[idx] = *(uint4*)tmp;
}

// ---------------------------------------------------------------------------
// Prep 2: W fp32 [K=1024][N=1024] -> Wt bf16 [N][K]. 64x64 LDS tiles.
// ---------------------------------------------------------------------------
__global__ __launch_bounds__(256) void transpose_w(const float* __restrict__ W,
                                                   ushort* __restrict__ Wt) {
  __shared__ ushort T[64][65];
  const int t = threadIdx.x;
  const int k0 = blockIdx.x * 64, n0 = blockIdx.y * 64;
  #pragma unroll
  for (int i = 0; i < 16; ++i) {
    int e = t + i * 256, r = e >> 6, c = e & 63;
    T[c][r] = f2b(W[(size_t)(k0 + r) * D_ + n0 + c]);
  }
  __syncthreads();
  #pragma unroll
  for (int i = 0; i < 16; ++i) {
    int e = t + i * 256, r = e >> 6, c = e & 63;
    Wt[(size_t)(n0 + r) * D_ + k0 + c] = T[r][c];
  }
}

// ---------------------------------------------------------------------------
// MFMA GEMM, m97-style K-loop: BM=BN=128, BK=32, 4 waves 2x2, 4x4 frags/wave.
// Staging: global_load_lds width-16, unpadded [128][32] LDS, XOR-block swizzle.
// MODE 0: PLAIN epilogue -> dense bf16 [4096][1024] per matrix (bias only).
// MODE 2: fp32 [M][N] + bias (final projection), direct stores.
// ---------------------------------------------------------------------------
template <int MODE>
__global__ __launch_bounds__(256) void gemm_mfma(
    const ushort* __restrict__ A0, const ushort* __restrict__ A1,
    const ushort* __restrict__ A2, const ushort* __restrict__ Bt,
    const float* __restrict__ bb0, const float* __restrict__ bb1,
    const float* __restrict__ bb2,
    ushort* __restrict__ oq, ushort* __restrict__ ok, ushort* __restrict__ ov,
    float* __restrict__ oo) {
  __shared__ ushort As[128 * 32];
  __shared__ ushort Bs[128 * 32];
  __shared__ ushort Es[(MODE == 0) ? 9216 : 1];  // [64][144] epilogue scratch

  const int t = threadIdx.x, w = t >> 6, l = t & 63;
  const int m0 = blockIdx.x * 128, n0 = blockIdx.y * 128;
  const int wm = (w >> 1) * 64, wn = (w & 1) * 64;
  const int lm = l & 15, h8 = (l >> 4) * 8, q4 = (l >> 4) * 4;
  const int hb = l >> 4;  // logical 16B block 0..3 of the K dim

  const ushort* A;
  const float* bias;
  int mat = 0;
  if constexpr (MODE == 0) {
    mat = n0 >> 10;
    A = (mat == 0) ? A0 : (mat == 1) ? A1 : A2;
    bias = (mat == 0) ? bb0 : (mat == 1) ? bb1 : bb2;
  } else {
    A = A0; bias = bb0;
  }

  const int srow = w * 32 + (l >> 2);
  const int pb = l & 3;
  const int lb = pb ^ (srow & 3);
  const ushort* gA = A + (size_t)(m0 + srow) * D_ + lb * 8;
  const ushort* gB = Bt + (size_t)(n0 + srow) * D_ + lb * 8;
  ushort* lA = As + w * 1024;
  ushort* lB = Bs + w * 1024;

  f4 acc[4][4];
  #pragma unroll
  for (int i = 0; i < 4; ++i)
    #pragma unroll
    for (int j = 0; j < 4; ++j) acc[i][j] = (f4){0.f, 0.f, 0.f, 0.f};

  for (int k0 = 0; k0 < D_; k0 += 32) {
    async16(gA + k0, lA);
    async16(gA + 16 * D_ + k0, lA + 512);
    async16(gB + k0, lB);
    async16(gB + 16 * D_ + k0, lB + 512);
    __syncthreads();
    s8 af[4], bfr[4];
    #pragma unroll
    for (int mt = 0; mt < 4; ++mt) {
      int ra = wm + mt * 16 + lm;
      af[mt] = *(const s8*)&As[ra * 32 + ((hb ^ (ra & 3)) << 3)];
    }
    #pragma unroll
    for (int nt = 0; nt < 4; ++nt) {
      int rb = wn + nt * 16 + lm;
      bfr[nt] = *(const s8*)&Bs[rb * 32 + ((hb ^ (rb & 3)) << 3)];
    }
    #pragma unroll
    for (int mt = 0; mt < 4; ++mt)
      #pragma unroll
      for (int nt = 0; nt < 4; ++nt)
        acc[mt][nt] = __builtin_amdgcn_mfma_f32_16x16x32_bf16(af[mt], bfr[nt], acc[mt][nt], 0, 0, 0);
    __syncthreads();
  }

  // ---- epilogue ----
  if constexpr (MODE == 2) {
    #pragma unroll
    for (int nt = 0; nt < 4; ++nt) {
      int n = n0 + wn + nt * 16 + lm;
      float bv = bias[n];
      #pragma unroll
      for (int mt = 0; mt < 4; ++mt)
        #pragma unroll
        for (int r = 0; r < 4; ++r)
          oo[(size_t)(m0 + wm + mt * 16 + q4 + r) * D_ + n] = acc[mt][nt][r] + bv;
    }
  } else {
    // plain dense store: dst[m][1024], bias + bf16, via LDS for 16B coalescing
    ushort* dst = (mat == 0) ? oq : (mat == 1) ? ok : ov;
    const int nm0 = n0 & 1023;
    #pragma unroll
    for (int p = 0; p < 2; ++p) {
      if ((w >> 1) == p) {
        #pragma unroll
        for (int nt = 0; nt < 4; ++nt) {
          int col = wn + nt * 16 + lm;
          float bv = bias[nm0 + col];
          #pragma unroll
          for (int mt = 0; mt < 4; ++mt)
            #pragma unroll
            for (int r = 0; r < 4; ++r)
              Es[(mt * 16 + q4 + r) * 144 + col] = f2b(acc[mt][nt][r] + bv);
        }
      }
      __syncthreads();
      #pragma unroll
      for (int i = 0; i < 4; ++i) {
        int e = t + i * 256, row = e >> 4, ch = e & 15;
        *(uint4*)&dst[(size_t)(m0 + p * 64 + row) * D_ + nm0 + ch * 8] =
            *(const uint4*)&Es[row * 144 + ch * 8];
      }
      __syncthreads();
    }
  }
}

// ---------------------------------------------------------------------------
// RoPE + relayout pass (memory-bound). Grid (32 bh, 32 s-tiles), 256 thr.
// Q/K: read dense [m][1024] bf16, apply reference RoPE (+0.125 scale on Q),
//      write [bh][s][dk]. V: read dense, LDS-transpose, write [bh][dk][s].
// ---------------------------------------------------------------------------
__global__ __launch_bounds__(256) void rope_pass(
    const ushort* __restrict__ qtmp, const ushort* __restrict__ ktmp,
    const ushort* __restrict__ vtmp,
    ushort* __restrict__ qfb, ushort* __restrict__ kfb,
    ushort* __restrict__ vtb) {
  __shared__ ushort T[64][72];
  const int t = threadIdx.x;
  const int bh = blockIdx.x, st = blockIdx.y;
  const int b = bh >> 4, h = bh & 15;
  const int s0 = st * 64;
  const int r = t >> 2, c0 = (t & 3) * 16;
  const int s = s0 + r;

  // per-thread trig tables for dk = c0..c0+15
  float cs[16], sn[16];
  const float pos = (float)s;
  #pragma unroll
  for (int j = 0; j < 16; ++j) {
    float invf = exp2f(-(float)((c0 + j) & 31) * ROPE_C);
    __sincosf(pos * invf, &sn[j], &cs[j]);
  }

  const size_t src = ((size_t)(b * S_ + s)) * D_ + h * 64 + c0;
  const size_t dstqk = ((size_t)bh * S_ + s) * DK_ + c0;

  #pragma unroll
  for (int tensor = 0; tensor < 2; ++tensor) {
    const ushort* in = tensor ? ktmp : qtmp;
    ushort* out = tensor ? kfb : qfb;
    const float scale = tensor ? 1.f : 0.125f;
    uint4 raw0 = *(const uint4*)&in[src];
    uint4 raw1 = *(const uint4*)&in[src + 8];
    ushort xr[16];
    *(uint4*)&xr[0] = raw0;
    *(uint4*)&xr[8] = raw1;
    float x[16];
    #pragma unroll
    for (int j = 0; j < 16; ++j) x[j] = b2f(xr[j]);
    ushort o[16];
    #pragma unroll
    for (int j = 0; j < 16; j += 2) {
      float e = x[j] * cs[j] - x[j + 1] * sn[j + 1];
      float d = x[j] * sn[j] + x[j + 1] * cs[j + 1];
      o[j] = f2b(e * scale);
      o[j + 1] = f2b(d * scale);
    }
    *(uint4*)&out[dstqk] = *(const uint4*)&o[0];
    *(uint4*)&out[dstqk + 8] = *(const uint4*)&o[8];
  }

  // V: transpose 64x64 tile via LDS
  {
    uint4 raw0 = *(const uint4*)&vtmp[src];
    uint4 raw1 = *(const uint4*)&vtmp[src + 8];
    ushort xr[16];
    *(uint4*)&xr[0] = raw0;
    *(uint4*)&xr[8] = raw1;
    #pragma unroll
    for (int j = 0; j < 16; ++j) T[c0 + j][r] = xr[j];
    __syncthreads();
    // thread r owns dk-row r, cols (s) c0..c0+15
    const size_t dstv = ((size_t)bh * DK_ + r) * S_ + s0 + c0;
    *(uint4*)&vtb[dstv] = *(const uint4*)&T[r][c0];
    *(uint4*)&vtb[dstv + 8] = *(const uint4*)&T[r][c0 + 8];
  }
}

// ---------------------------------------------------------------------------
// MFMA flash attention. Grid (32 bh, 32 qt), 256 thr = 4 waves x 16 Q-rows.
// Q pre-scaled. qf/kf: [bh][s][64] bf16; vtf: [bh][dk][2048] bf16.
// ctx out bf16 [B*S][1024], staged through Qs for coalesced 16B stores.
// ---------------------------------------------------------------------------
__global__ __launch_bounds__(256) void attn_mfma(const ushort* __restrict__ qf,
                                                 const ushort* __restrict__ kf,
                                                 const ushort* __restrict__ vtf,
                                                 ushort* __restrict__ ctx) {
  __shared__ ushort Qs[64][72], Ks[64][72], Vts[64][72], Ps[64][72];

  const int t = threadIdx.x, w = t >> 6, l = t & 63;
  const int bh = blockIdx.x, qt = blockIdx.y;
  const int i0 = qt * 64;
  const int lm = l & 15, h8 = (l >> 4) * 8, q4 = (l >> 4) * 4, w16 = w * 16;
  const size_t base = (size_t)bh * S_ * DK_;

  #pragma unroll
  for (int i = 0; i < 2; ++i) {
    int g = t + i * 256, r = g >> 3, c = (g & 7) * 8;
    *(uint4*)&Qs[r][c] = *(const uint4*)&qf[base + (size_t)(i0 + r) * DK_ + c];
  }

  f4 O[4];
  #pragma unroll
  for (int i = 0; i < 4; ++i) O[i] = (f4){0.f, 0.f, 0.f, 0.f};
  float m_[4] = {-1e30f, -1e30f, -1e30f, -1e30f};
  float l_[4] = {0.f, 0.f, 0.f, 0.f};

  for (int jt = 0; jt <= qt; ++jt) {
    const int j0 = jt * 64;
    #pragma unroll
    for (int i = 0; i < 2; ++i) {
      int g = t + i * 256, r = g >> 3, c = (g & 7) * 8;
      *(uint4*)&Ks[r][c] = *(const uint4*)&kf[base + (size_t)(j0 + r) * DK_ + c];
      *(uint4*)&Vts[r][c] = *(const uint4*)&vtf[base + (size_t)r * S_ + j0 + c];
    }
    __syncthreads();

    s8 aq0 = *(const s8*)&Qs[w16 + lm][h8];
    s8 aq1 = *(const s8*)&Qs[w16 + lm][h8 + 32];
    f4 sc[4];
    #pragma unroll
    for (int nt = 0; nt < 4; ++nt) {
      s8 b0 = *(const s8*)&Ks[nt * 16 + lm][h8];
      s8 b1 = *(const s8*)&Ks[nt * 16 + lm][h8 + 32];
      f4 a = (f4){0.f, 0.f, 0.f, 0.f};
      a = __builtin_amdgcn_mfma_f32_16x16x32_bf16(aq0, b0, a, 0, 0, 0);
      a = __builtin_amdgcn_mfma_f32_16x16x32_bf16(aq1, b1, a, 0, 0, 0);
      sc[nt] = a;
    }
    if (jt == qt) {
      #pragma unroll
      for (int nt = 0; nt < 4; ++nt)
        #pragma unroll
        for (int r = 0; r < 4; ++r)
          if (nt * 16 + lm > w16 + q4 + r) sc[nt][r] = -1e30f;
    }
    float rmax[4];
    #pragma unroll
    for (int r = 0; r < 4; ++r)
      rmax[r] = fmaxf(fmaxf(sc[0][r], sc[1][r]), fmaxf(sc[2][r], sc[3][r]));
    #pragma unroll
    for (int off = 1; off < 16; off <<= 1)
      #pragma unroll
      for (int r = 0; r < 4; ++r) rmax[r] = fmaxf(rmax[r], __shfl_xor(rmax[r], off));
    float alpha[4];
    #pragma unroll
    for (int r = 0; r < 4; ++r) {
      float mn = fmaxf(m_[r], rmax[r]);
      alpha[r] = exp2f((m_[r] - mn) * LOG2E);
      m_[r] = mn;
    }
    float rsum[4] = {0.f, 0.f, 0.f, 0.f};
    #pragma unroll
    for (int nt = 0; nt < 4; ++nt)
      #pragma unroll
      for (int r = 0; r < 4; ++r) {
        float p = exp2f((sc[nt][r] - m_[r]) * LOG2E);
        sc[nt][r] = p;
        rsum[r] += p;
      }
    #pragma unroll
    for (int off = 1; off < 16; off <<= 1)
      #pragma unroll
      for (int r = 0; r < 4; ++r) rsum[r] += __shfl_xor(rsum[r], off);
    #pragma unroll
    for (int r = 0; r < 4; ++r) l_[r] = l_[r] * alpha[r] + rsum[r];
    #pragma unroll
    for (int nt = 0; nt < 4; ++nt)
      #pragma unroll
      for (int r = 0; r < 4; ++r)
        Ps[w16 + q4 + r][nt * 16 + lm] = f2b(sc[nt][r]);
    #pragma unroll
    for (int nt = 0; nt < 4; ++nt)
      #pragma unroll
      for (int r = 0; r < 4; ++r) O[nt][r] *= alpha[r];
    s8 ap0 = *(const s8*)&Ps[w16 + lm][h8];
    s8 ap1 = *(const s8*)&Ps[w16 + lm][h8 + 32];
    #pragma unroll
    for (int nt = 0; nt < 4; ++nt) {
      s8 v0 = *(const s8*)&Vts[nt * 16 + lm][h8];
      s8 v1 = *(const s8*)&Vts[nt * 16 + lm][h8 + 32];
      O[nt] = __builtin_amdgcn_mfma_f32_16x16x32_bf16(ap0, v0, O[nt], 0, 0, 0);
      O[nt] = __builtin_amdgcn_mfma_f32_16x16x32_bf16(ap1, v1, O[nt], 0, 0, 0);
    }
    __syncthreads();
  }

  float inv[4];
  #pragma unroll
  for (int r = 0; r < 4; ++r) inv[r] = 1.f / l_[r];
  #pragma unroll
  for (int nt = 0; nt < 4; ++nt)
    #pragma unroll
    for (int r = 0; r < 4; ++r)
      Qs[w16 + q4 + r][nt * 16 + lm] = f2b(O[nt][r] * inv[r]);
  __syncthreads();
  const int b = bh >> 4, h = bh & 15;
  #pragma unroll
  for (int i = 0; i < 2; ++i) {
    int e = t + i * 256;
    int row = e >> 3, ch = e & 7;
    int s = i0 + row;
    *(uint4*)&ctx[((size_t)(b * S_ + s)) * D_ + h * 64 + ch * 8] =
        *(const uint4*)&Qs[row][ch * 8];
  }
}

// ---------------------------------------------------------------------------
extern "C" void kernel_launch(void* const* d_in, const int* in_sizes, int n_in,
                              void* d_out, int out_size, void* d_ws, size_t ws_size,
                              hipStream_t stream) {
  const float* q_in = (const float*)d_in[0];
  const float* k_in = (const float*)d_in[1];
  const float* v_in = (const float*)d_in[2];
  const float* Wq = (const float*)d_in[3];
  const float* bq = (const float*)d_in[4];
  const float* Wk = (const float*)d_in[5];
  const float* bk = (const float*)d_in[6];
  const float* Wv = (const float*)d_in[7];
  const float* bv = (const float*)d_in[8];
  const float* Wo = (const float*)d_in[9];
  const float* bo = (const float*)d_in[10];

  const size_t NE = (size_t)B_ * S_ * D_;  // 4,194,304
  ushort* Xbq = (ushort*)d_ws;
  ushort* Xbk = Xbq + NE;
  ushort* Xbv = Xbk + NE;
  ushort* Wtqkv = Xbv + NE;              // [3072][1024] bf16
  ushort* Wto = Wtqkv + 3 * 1024 * 1024;
  ushort* qtmp = Wto + 1024 * 1024;      // dense [4096][1024] bf16
  ushort* ktmp = qtmp + NE;
  ushort* vtmp = ktmp + NE;
  ushort* qfb = vtmp + NE;               // [bh][s][dk]
  ushort* kfb = qfb + NE;
  ushort* vtb = kfb + NE;                // [bh][dk][s]
  ushort* ctxb = qtmp;                   // alias: qtmp dead after rope_pass

  conv_x<<<2048, 256, 0, stream>>>(q_in, Xbq);
  conv_x<<<2048, 256, 0, stream>>>(k_in, Xbk);
  conv_x<<<2048, 256, 0, stream>>>(v_in, Xbv);
  transpose_w<<<dim3(16, 16), 256, 0, stream>>>(Wq, Wtqkv);
  transpose_w<<<dim3(16, 16), 256, 0, stream>>>(Wk, Wtqkv + 1024 * 1024);
  transpose_w<<<dim3(16, 16), 256, 0, stream>>>(Wv, Wtqkv + 2 * 1024 * 1024);
  transpose_w<<<dim3(16, 16), 256, 0, stream>>>(Wo, Wto);

  gemm_mfma<0><<<dim3(32, 24), 256, 0, stream>>>(
      Xbq, Xbk, Xbv, Wtqkv, bq, bk, bv, qtmp, ktmp, vtmp, nullptr);

  rope_pass<<<dim3(32, 32), 256, 0, stream>>>(qtmp, ktmp, vtmp, qfb, kfb, vtb);

  attn_mfma<<<dim3(32, 32), 256, 0, stream>>>(qfb, kfb, vtb, ctxb);

  gemm_mfma<2><<<dim3(32, 8), 256, 0, stream>>>(
      ctxb, ctxb, ctxb, Wto, bo, bo, bo, nullptr, nullptr, nullptr,
      (float*)d_out);
}

// Round 8
// 280.363 us; speedup vs baseline: 6.5870x; 1.0809x over previous
//
#include <hip/hip_runtime.h>
#include <hip/hip_bf16.h>
#include <math.h>

// (B,S,D,H) = (2,2048,1024,16), DK=64
#define B_ 2
#define S_ 2048
#define D_ 1024
#define H_ 16
#define DK_ 64

#define ROPE_C 0.4152410118609203f   // log2(10000)/32
#define LOG2E 1.4426950408889634f

typedef float f4 __attribute__((ext_vector_type(4)));
typedef short s8 __attribute__((ext_vector_type(8)));

__device__ __forceinline__ ushort f2b(float f) {
  union { float f; uint u; } v; v.f = f;
  uint u = v.u + 0x7fffu + ((v.u >> 16) & 1u);
  return (ushort)(u >> 16);
}

__device__ __forceinline__ float b2f(ushort u) {
  union { uint u; float f; } v; v.u = ((uint)u) << 16;
  return v.f;
}

// async global->LDS DMA, 16 B per lane. LDS dest = wave-uniform base + lane*16.
__device__ __forceinline__ void async16(const ushort* g, ushort* l) {
  __builtin_amdgcn_global_load_lds(
      (const __attribute__((address_space(1))) uint*)g,
      (__attribute__((address_space(3))) uint*)l, 16, 0, 0);
}

// ---------------------------------------------------------------------------
// Prep 1: fp32 -> bf16 flat convert (4M elems). 8 elems/thread.
// ---------------------------------------------------------------------------
__global__ __launch_bounds__(256) void conv_x(const float* __restrict__ in,
                                              ushort* __restrict__ out) {
  int idx = (blockIdx.x * 256 + threadIdx.x) * 8;
  float4 a = *(const float4*)&in[idx];
  float4 b = *(const float4*)&in[idx + 4];
  ushort tmp[8] = {f2b(a.x), f2b(a.y), f2b(a.z), f2b(a.w),
                   f2b(b.x), f2b(b.y), f2b(b.z), f2b(b.w)};
  *(uint4*)&out[idx] = *(uint4*)tmp;
}

// ---------------------------------------------------------------------------
// Prep 2: W fp32 [K=1024][N=1024] -> Wt bf16 [N][K]. 64x64 LDS tiles.
// ---------------------------------------------------------------------------
__global__ __launch_bounds__(256) void transpose_w(const float* __restrict__ W,
                                                   ushort* __restrict__ Wt) {
  __shared__ ushort T[64][65];
  const int t = threadIdx.x;
  const int k0 = blockIdx.x * 64, n0 = blockIdx.y * 64;
  #pragma unroll
  for (int i = 0; i < 16; ++i) {
    int e = t + i * 256, r = e >> 6, c = e & 63;
    T[c][r] = f2b(W[(size_t)(k0 + r) * D_ + n0 + c]);
  }
  __syncthreads();
  #pragma unroll
  for (int i = 0; i < 16; ++i) {
    int e = t + i * 256, r = e >> 6, c = e & 63;
    Wt[(size_t)(n0 + r) * D_ + k0 + c] = T[r][c];
  }
}

// ---------------------------------------------------------------------------
// MFMA GEMM, m97-style K-loop: BM=BN=128, BK=32, 4 waves 2x2, 4x4 frags/wave.
// Staging: global_load_lds width-16, unpadded [128][32] LDS, XOR-block swizzle.
// MODE 0: PLAIN epilogue -> dense bf16 [4096][1024] per matrix (bias only).
// MODE 2: fp32 [M][N] + bias (final projection), direct stores.
// ---------------------------------------------------------------------------
template <int MODE>
__global__ __launch_bounds__(256) void gemm_mfma(
    const ushort* __restrict__ A0, const ushort* __restrict__ A1,
    const ushort* __restrict__ A2, const ushort* __restrict__ Bt,
    const float* __restrict__ bb0, const float* __restrict__ bb1,
    const float* __restrict__ bb2,
    ushort* __restrict__ oq, ushort* __restrict__ ok, ushort* __restrict__ ov,
    float* __restrict__ oo) {
  __shared__ ushort As[128 * 32];
  __shared__ ushort Bs[128 * 32];
  __shared__ ushort Es[(MODE == 0) ? 9216 : 1];  // [64][144] epilogue scratch

  const int t = threadIdx.x, w = t >> 6, l = t & 63;
  const int m0 = blockIdx.x * 128, n0 = blockIdx.y * 128;
  const int wm = (w >> 1) * 64, wn = (w & 1) * 64;
  const int lm = l & 15, h8 = (l >> 4) * 8, q4 = (l >> 4) * 4;
  const int hb = l >> 4;

  const ushort* A;
  const float* bias;
  int mat = 0;
  if constexpr (MODE == 0) {
    mat = n0 >> 10;
    A = (mat == 0) ? A0 : (mat == 1) ? A1 : A2;
    bias = (mat == 0) ? bb0 : (mat == 1) ? bb1 : bb2;
  } else {
    A = A0; bias = bb0;
  }

  const int srow = w * 32 + (l >> 2);
  const int pb = l & 3;
  const int lb = pb ^ (srow & 3);
  const ushort* gA = A + (size_t)(m0 + srow) * D_ + lb * 8;
  const ushort* gB = Bt + (size_t)(n0 + srow) * D_ + lb * 8;
  ushort* lA = As + w * 1024;
  ushort* lB = Bs + w * 1024;

  f4 acc[4][4];
  #pragma unroll
  for (int i = 0; i < 4; ++i)
    #pragma unroll
    for (int j = 0; j < 4; ++j) acc[i][j] = (f4){0.f, 0.f, 0.f, 0.f};

  for (int k0 = 0; k0 < D_; k0 += 32) {
    async16(gA + k0, lA);
    async16(gA + 16 * D_ + k0, lA + 512);
    async16(gB + k0, lB);
    async16(gB + 16 * D_ + k0, lB + 512);
    __syncthreads();
    s8 af[4], bfr[4];
    #pragma unroll
    for (int mt = 0; mt < 4; ++mt) {
      int ra = wm + mt * 16 + lm;
      af[mt] = *(const s8*)&As[ra * 32 + ((hb ^ (ra & 3)) << 3)];
    }
    #pragma unroll
    for (int nt = 0; nt < 4; ++nt) {
      int rb = wn + nt * 16 + lm;
      bfr[nt] = *(const s8*)&Bs[rb * 32 + ((hb ^ (rb & 3)) << 3)];
    }
    #pragma unroll
    for (int mt = 0; mt < 4; ++mt)
      #pragma unroll
      for (int nt = 0; nt < 4; ++nt)
        acc[mt][nt] = __builtin_amdgcn_mfma_f32_16x16x32_bf16(af[mt], bfr[nt], acc[mt][nt], 0, 0, 0);
    __syncthreads();
  }

  // ---- epilogue ----
  if constexpr (MODE == 2) {
    #pragma unroll
    for (int nt = 0; nt < 4; ++nt) {
      int n = n0 + wn + nt * 16 + lm;
      float bv = bias[n];
      #pragma unroll
      for (int mt = 0; mt < 4; ++mt)
        #pragma unroll
        for (int r = 0; r < 4; ++r)
          oo[(size_t)(m0 + wm + mt * 16 + q4 + r) * D_ + n] = acc[mt][nt][r] + bv;
    }
  } else {
    ushort* dst = (mat == 0) ? oq : (mat == 1) ? ok : ov;
    const int nm0 = n0 & 1023;
    #pragma unroll
    for (int p = 0; p < 2; ++p) {
      if ((w >> 1) == p) {
        #pragma unroll
        for (int nt = 0; nt < 4; ++nt) {
          int col = wn + nt * 16 + lm;
          float bv = bias[nm0 + col];
          #pragma unroll
          for (int mt = 0; mt < 4; ++mt)
            #pragma unroll
            for (int r = 0; r < 4; ++r)
              Es[(mt * 16 + q4 + r) * 144 + col] = f2b(acc[mt][nt][r] + bv);
        }
      }
      __syncthreads();
      #pragma unroll
      for (int i = 0; i < 4; ++i) {
        int e = t + i * 256, row = e >> 4, ch = e & 15;
        *(uint4*)&dst[(size_t)(m0 + p * 64 + row) * D_ + nm0 + ch * 8] =
            *(const uint4*)&Es[row * 144 + ch * 8];
      }
      __syncthreads();
    }
  }
}

// ---------------------------------------------------------------------------
// RoPE + relayout pass (memory-bound). Grid (32 bh, 32 s-tiles), 256 thr.
// ---------------------------------------------------------------------------
__global__ __launch_bounds__(256) void rope_pass(
    const ushort* __restrict__ qtmp, const ushort* __restrict__ ktmp,
    const ushort* __restrict__ vtmp,
    ushort* __restrict__ qfb, ushort* __restrict__ kfb,
    ushort* __restrict__ vtb) {
  __shared__ ushort T[64][72];
  const int t = threadIdx.x;
  const int bh = blockIdx.x, st = blockIdx.y;
  const int b = bh >> 4, h = bh & 15;
  const int s0 = st * 64;
  const int r = t >> 2, c0 = (t & 3) * 16;
  const int s = s0 + r;

  float cs[16], sn[16];
  const float pos = (float)s;
  #pragma unroll
  for (int j = 0; j < 16; ++j) {
    float invf = exp2f(-(float)((c0 + j) & 31) * ROPE_C);
    __sincosf(pos * invf, &sn[j], &cs[j]);
  }

  const size_t src = ((size_t)(b * S_ + s)) * D_ + h * 64 + c0;
  const size_t dstqk = ((size_t)bh * S_ + s) * DK_ + c0;

  #pragma unroll
  for (int tensor = 0; tensor < 2; ++tensor) {
    const ushort* in = tensor ? ktmp : qtmp;
    ushort* out = tensor ? kfb : qfb;
    const float scale = tensor ? 1.f : 0.125f;
    uint4 raw0 = *(const uint4*)&in[src];
    uint4 raw1 = *(const uint4*)&in[src + 8];
    ushort xr[16];
    *(uint4*)&xr[0] = raw0;
    *(uint4*)&xr[8] = raw1;
    float x[16];
    #pragma unroll
    for (int j = 0; j < 16; ++j) x[j] = b2f(xr[j]);
    ushort o[16];
    #pragma unroll
    for (int j = 0; j < 16; j += 2) {
      float e = x[j] * cs[j] - x[j + 1] * sn[j + 1];
      float d = x[j] * sn[j] + x[j + 1] * cs[j + 1];
      o[j] = f2b(e * scale);
      o[j + 1] = f2b(d * scale);
    }
    *(uint4*)&out[dstqk] = *(const uint4*)&o[0];
    *(uint4*)&out[dstqk + 8] = *(const uint4*)&o[8];
  }

  {
    uint4 raw0 = *(const uint4*)&vtmp[src];
    uint4 raw1 = *(const uint4*)&vtmp[src + 8];
    ushort xr[16];
    *(uint4*)&xr[0] = raw0;
    *(uint4*)&xr[8] = raw1;
    #pragma unroll
    for (int j = 0; j < 16; ++j) T[c0 + j][r] = xr[j];
    __syncthreads();
    const size_t dstv = ((size_t)bh * DK_ + r) * S_ + s0 + c0;
    *(uint4*)&vtb[dstv] = *(const uint4*)&T[r][c0];
    *(uint4*)&vtb[dstv + 8] = *(const uint4*)&T[r][c0 + 8];
  }
}

// ---------------------------------------------------------------------------
// MFMA flash attention, transposed-scores variant.
// Grid (32 bh, 32 qt), 256 thr = 4 waves x 16 Q-rows.
// S^T = K @ Q^T  (swap MFMA operands): C-layout col (lane&15) = Q-row, so
// softmax reductions are 15 in-reg ops + 2 shfl, state is 1 scalar/thread,
// and P->LDS A-layout writes pack into 4x 8B stores (r = consecutive keys).
// ---------------------------------------------------------------------------
__global__ __launch_bounds__(256) void attn_mfma(const ushort* __restrict__ qf,
                                                 const ushort* __restrict__ kf,
                                                 const ushort* __restrict__ vtf,
                                                 ushort* __restrict__ ctx) {
  __shared__ ushort Qs[64][72], Ks[64][72], Vts[64][72], Ps[64][72];

  const int t = threadIdx.x, w = t >> 6, l = t & 63;
  const int bh = blockIdx.x, qt = blockIdx.y;
  const int i0 = qt * 64;
  const int lm = l & 15, h8 = (l >> 4) * 8, q4 = (l >> 4) * 4, w16 = w * 16;
  const size_t base = (size_t)bh * S_ * DK_;

  #pragma unroll
  for (int i = 0; i < 2; ++i) {
    int g = t + i * 256, r = g >> 3, c = (g & 7) * 8;
    *(uint4*)&Qs[r][c] = *(const uint4*)&qf[base + (size_t)(i0 + r) * DK_ + c];
  }

  f4 O[4];
  #pragma unroll
  for (int i = 0; i < 4; ++i) O[i] = (f4){0.f, 0.f, 0.f, 0.f};
  float m_ = -1e30f, l_ = 0.f;  // state for Q-row w16 + lm

  for (int jt = 0; jt <= qt; ++jt) {
    const int j0 = jt * 64;
    #pragma unroll
    for (int i = 0; i < 2; ++i) {
      int g = t + i * 256, r = g >> 3, c = (g & 7) * 8;
      *(uint4*)&Ks[r][c] = *(const uint4*)&kf[base + (size_t)(j0 + r) * DK_ + c];
      *(uint4*)&Vts[r][c] = *(const uint4*)&vtf[base + (size_t)r * S_ + j0 + c];
    }
    __syncthreads();

    // S^T = K @ Q^T : rows (q4+r) = keys, cols (lm) = Q-rows
    s8 bq0 = *(const s8*)&Qs[w16 + lm][h8];
    s8 bq1 = *(const s8*)&Qs[w16 + lm][h8 + 32];
    f4 st[4];
    #pragma unroll
    for (int nt = 0; nt < 4; ++nt) {
      s8 a0 = *(const s8*)&Ks[nt * 16 + lm][h8];
      s8 a1 = *(const s8*)&Ks[nt * 16 + lm][h8 + 32];
      f4 a = (f4){0.f, 0.f, 0.f, 0.f};
      a = __builtin_amdgcn_mfma_f32_16x16x32_bf16(a0, bq0, a, 0, 0, 0);
      a = __builtin_amdgcn_mfma_f32_16x16x32_bf16(a1, bq1, a, 0, 0, 0);
      st[nt] = a;
    }
    if (jt == qt) {  // causal: key nt*16+q4+r vs qrow w16+lm
      #pragma unroll
      for (int nt = 0; nt < 4; ++nt)
        #pragma unroll
        for (int r = 0; r < 4; ++r)
          if (nt * 16 + q4 + r > w16 + lm) st[nt][r] = -1e30f;
    }
    // row max: 15 in-reg + 2 shfl
    float pm = st[0][0];
    #pragma unroll
    for (int nt = 0; nt < 4; ++nt)
      #pragma unroll
      for (int r = 0; r < 4; ++r) pm = fmaxf(pm, st[nt][r]);
    pm = fmaxf(pm, __shfl_xor(pm, 16));
    pm = fmaxf(pm, __shfl_xor(pm, 32));
    float mn = fmaxf(m_, pm);
    float alpha = exp2f((m_ - mn) * LOG2E);
    m_ = mn;
    // exp + row sum
    float ps = 0.f;
    #pragma unroll
    for (int nt = 0; nt < 4; ++nt)
      #pragma unroll
      for (int r = 0; r < 4; ++r) {
        float p = exp2f((st[nt][r] - mn) * LOG2E);
        st[nt][r] = p;
        ps += p;
      }
    ps += __shfl_xor(ps, 16);
    ps += __shfl_xor(ps, 32);
    l_ = l_ * alpha + ps;
    // P -> LDS A-layout [qrow][key]: 4x packed 8B stores (keys nt*16+q4+0..3)
    #pragma unroll
    for (int nt = 0; nt < 4; ++nt) {
      ushort pk[4] = {f2b(st[nt][0]), f2b(st[nt][1]), f2b(st[nt][2]), f2b(st[nt][3])};
      *(uint2*)&Ps[w16 + lm][nt * 16 + q4] = *(const uint2*)pk;
    }
    // alpha for O rows q4+r (held at lanes 0..15)
    float ar[4];
    #pragma unroll
    for (int r = 0; r < 4; ++r) ar[r] = __shfl(alpha, q4 + r);
    #pragma unroll
    for (int nt = 0; nt < 4; ++nt)
      #pragma unroll
      for (int r = 0; r < 4; ++r) O[nt][r] *= ar[r];
    // PV
    s8 ap0 = *(const s8*)&Ps[w16 + lm][h8];
    s8 ap1 = *(const s8*)&Ps[w16 + lm][h8 + 32];
    #pragma unroll
    for (int nt = 0; nt < 4; ++nt) {
      s8 v0 = *(const s8*)&Vts[nt * 16 + lm][h8];
      s8 v1 = *(const s8*)&Vts[nt * 16 + lm][h8 + 32];
      O[nt] = __builtin_amdgcn_mfma_f32_16x16x32_bf16(ap0, v0, O[nt], 0, 0, 0);
      O[nt] = __builtin_amdgcn_mfma_f32_16x16x32_bf16(ap1, v1, O[nt], 0, 0, 0);
    }
    __syncthreads();
  }

  // epilogue: 1/l for rows q4+r via shfl, stage in Qs, coalesced 16B stores
  float il[4];
  #pragma unroll
  for (int r = 0; r < 4; ++r) {
    float lr = __shfl(l_, q4 + r);
    il[r] = 1.f / lr;
  }
  #pragma unroll
  for (int nt = 0; nt < 4; ++nt)
    #pragma unroll
    for (int r = 0; r < 4; ++r)
      Qs[w16 + q4 + r][nt * 16 + lm] = f2b(O[nt][r] * il[r]);
  __syncthreads();
  const int b = bh >> 4, h = bh & 15;
  #pragma unroll
  for (int i = 0; i < 2; ++i) {
    int e = t + i * 256;
    int row = e >> 3, ch = e & 7;
    int s = i0 + row;
    *(uint4*)&ctx[((size_t)(b * S_ + s)) * D_ + h * 64 + ch * 8] =
        *(const uint4*)&Qs[row][ch * 8];
  }
}

// ---------------------------------------------------------------------------
extern "C" void kernel_launch(void* const* d_in, const int* in_sizes, int n_in,
                              void* d_out, int out_size, void* d_ws, size_t ws_size,
                              hipStream_t stream) {
  const float* q_in = (const float*)d_in[0];
  const float* k_in = (const float*)d_in[1];
  const float* v_in = (const float*)d_in[2];
  const float* Wq = (const float*)d_in[3];
  const float* bq = (const float*)d_in[4];
  const float* Wk = (const float*)d_in[5];
  const float* bk = (const float*)d_in[6];
  const float* Wv = (const float*)d_in[7];
  const float* bv = (const float*)d_in[8];
  const float* Wo = (const float*)d_in[9];
  const float* bo = (const float*)d_in[10];

  const size_t NE = (size_t)B_ * S_ * D_;  // 4,194,304
  ushort* Xbq = (ushort*)d_ws;
  ushort* Xbk = Xbq + NE;
  ushort* Xbv = Xbk + NE;
  ushort* Wtqkv = Xbv + NE;              // [3072][1024] bf16
  ushort* Wto = Wtqkv + 3 * 1024 * 1024;
  ushort* qtmp = Wto + 1024 * 1024;      // dense [4096][1024] bf16
  ushort* ktmp = qtmp + NE;
  ushort* vtmp = ktmp + NE;
  ushort* qfb = vtmp + NE;               // [bh][s][dk]
  ushort* kfb = qfb + NE;
  ushort* vtb = kfb + NE;                // [bh][dk][s]
  ushort* ctxb = qtmp;                   // alias: qtmp dead after rope_pass

  conv_x<<<2048, 256, 0, stream>>>(q_in, Xbq);
  conv_x<<<2048, 256, 0, stream>>>(k_in, Xbk);
  conv_x<<<2048, 256, 0, stream>>>(v_in, Xbv);
  transpose_w<<<dim3(16, 16), 256, 0, stream>>>(Wq, Wtqkv);
  transpose_w<<<dim3(16, 16), 256, 0, stream>>>(Wk, Wtqkv + 1024 * 1024);
  transpose_w<<<dim3(16, 16), 256, 0, stream>>>(Wv, Wtqkv + 2 * 1024 * 1024);
  transpose_w<<<dim3(16, 16), 256, 0, stream>>>(Wo, Wto);

  gemm_mfma<0><<<dim3(32, 24), 256, 0, stream>>>(
      Xbq, Xbk, Xbv, Wtqkv, bq, bk, bv, qtmp, ktmp, vtmp, nullptr);

  rope_pass<<<dim3(32, 32), 256, 0, stream>>>(qtmp, ktmp, vtmp, qfb, kfb, vtb);

  attn_mfma<<<dim3(32, 32), 256, 0, stream>>>(qfb, kfb, vtb, ctxb);

  gemm_mfma<2><<<dim3(32, 8), 256, 0, stream>>>(
      ctxb, ctxb, ctxb, Wto, bo, bo, bo, nullptr, nullptr, nullptr,
      (float*)d_out);
}

// Round 9
// 277.228 us; speedup vs baseline: 6.6615x; 1.0113x over previous
//
#include <hip/hip_runtime.h>
#include <hip/hip_bf16.h>
#include <math.h>

// (B,S,D,H) = (2,2048,1024,16), DK=64
#define B_ 2
#define S_ 2048
#define D_ 1024
#define H_ 16
#define DK_ 64

#define ROPE_C 0.4152410118609203f   // log2(10000)/32
#define LOG2E 1.4426950408889634f

typedef float f4 __attribute__((ext_vector_type(4)));
typedef short s8 __attribute__((ext_vector_type(8)));

__device__ __forceinline__ ushort f2b(float f) {
  union { float f; uint u; } v; v.f = f;
  uint u = v.u + 0x7fffu + ((v.u >> 16) & 1u);
  return (ushort)(u >> 16);
}

__device__ __forceinline__ float b2f(ushort u) {
  union { uint u; float f; } v; v.u = ((uint)u) << 16;
  return v.f;
}

// async global->LDS DMA, 16 B per lane. LDS dest = wave-uniform base + lane*16.
__device__ __forceinline__ void async16(const ushort* g, ushort* l) {
  __builtin_amdgcn_global_load_lds(
      (const __attribute__((address_space(1))) uint*)g,
      (__attribute__((address_space(3))) uint*)l, 16, 0, 0);
}

// ---------------------------------------------------------------------------
// Prep 1: fp32 -> bf16 flat convert (4M elems). 8 elems/thread.
// ---------------------------------------------------------------------------
__global__ __launch_bounds__(256) void conv_x(const float* __restrict__ in,
                                              ushort* __restrict__ out) {
  int idx = (blockIdx.x * 256 + threadIdx.x) * 8;
  float4 a = *(const float4*)&in[idx];
  float4 b = *(const float4*)&in[idx + 4];
  ushort tmp[8] = {f2b(a.x), f2b(a.y), f2b(a.z), f2b(a.w),
                   f2b(b.x), f2b(b.y), f2b(b.z), f2b(b.w)};
  *(uint4*)&out[idx] = *(uint4*)tmp;
}

// ---------------------------------------------------------------------------
// Prep 2: W fp32 [K=1024][N=1024] -> Wt bf16 [N][K]. 64x64 LDS tiles.
// ---------------------------------------------------------------------------
__global__ __launch_bounds__(256) void transpose_w(const float* __restrict__ W,
                                                   ushort* __restrict__ Wt) {
  __shared__ ushort T[64][65];
  const int t = threadIdx.x;
  const int k0 = blockIdx.x * 64, n0 = blockIdx.y * 64;
  #pragma unroll
  for (int i = 0; i < 16; ++i) {
    int e = t + i * 256, r = e >> 6, c = e & 63;
    T[c][r] = f2b(W[(size_t)(k0 + r) * D_ + n0 + c]);
  }
  __syncthreads();
  #pragma unroll
  for (int i = 0; i < 16; ++i) {
    int e = t + i * 256, r = e >> 6, c = e & 63;
    Wt[(size_t)(n0 + r) * D_ + k0 + c] = T[r][c];
  }
}

// ---------------------------------------------------------------------------
// MFMA GEMM, m97-style K-loop: BM=BN=128, BK=32, 4 waves 2x2, 4x4 frags/wave.
// Staging: global_load_lds width-16, unpadded [128][32] LDS, XOR-block swizzle.
// MODE 0: PLAIN epilogue -> dense bf16 [4096][1024] per matrix (bias only).
// MODE 2: fp32 [M][N] + bias (final projection), direct stores.
// ---------------------------------------------------------------------------
template <int MODE>
__global__ __launch_bounds__(256) void gemm_mfma(
    const ushort* __restrict__ A0, const ushort* __restrict__ A1,
    const ushort* __restrict__ A2, const ushort* __restrict__ Bt,
    const float* __restrict__ bb0, const float* __restrict__ bb1,
    const float* __restrict__ bb2,
    ushort* __restrict__ oq, ushort* __restrict__ ok, ushort* __restrict__ ov,
    float* __restrict__ oo) {
  __shared__ ushort As[128 * 32];
  __shared__ ushort Bs[128 * 32];
  __shared__ ushort Es[(MODE == 0) ? 9216 : 1];  // [64][144] epilogue scratch

  const int t = threadIdx.x, w = t >> 6, l = t & 63;
  const int m0 = blockIdx.x * 128, n0 = blockIdx.y * 128;
  const int wm = (w >> 1) * 64, wn = (w & 1) * 64;
  const int lm = l & 15, h8 = (l >> 4) * 8, q4 = (l >> 4) * 4;
  const int hb = l >> 4;

  const ushort* A;
  const float* bias;
  int mat = 0;
  if constexpr (MODE == 0) {
    mat = n0 >> 10;
    A = (mat == 0) ? A0 : (mat == 1) ? A1 : A2;
    bias = (mat == 0) ? bb0 : (mat == 1) ? bb1 : bb2;
  } else {
    A = A0; bias = bb0;
  }

  const int srow = w * 32 + (l >> 2);
  const int pb = l & 3;
  const int lb = pb ^ (srow & 3);
  const ushort* gA = A + (size_t)(m0 + srow) * D_ + lb * 8;
  const ushort* gB = Bt + (size_t)(n0 + srow) * D_ + lb * 8;
  ushort* lA = As + w * 1024;
  ushort* lB = Bs + w * 1024;

  f4 acc[4][4];
  #pragma unroll
  for (int i = 0; i < 4; ++i)
    #pragma unroll
    for (int j = 0; j < 4; ++j) acc[i][j] = (f4){0.f, 0.f, 0.f, 0.f};

  for (int k0 = 0; k0 < D_; k0 += 32) {
    async16(gA + k0, lA);
    async16(gA + 16 * D_ + k0, lA + 512);
    async16(gB + k0, lB);
    async16(gB + 16 * D_ + k0, lB + 512);
    __syncthreads();
    s8 af[4], bfr[4];
    #pragma unroll
    for (int mt = 0; mt < 4; ++mt) {
      int ra = wm + mt * 16 + lm;
      af[mt] = *(const s8*)&As[ra * 32 + ((hb ^ (ra & 3)) << 3)];
    }
    #pragma unroll
    for (int nt = 0; nt < 4; ++nt) {
      int rb = wn + nt * 16 + lm;
      bfr[nt] = *(const s8*)&Bs[rb * 32 + ((hb ^ (rb & 3)) << 3)];
    }
    #pragma unroll
    for (int mt = 0; mt < 4; ++mt)
      #pragma unroll
      for (int nt = 0; nt < 4; ++nt)
        acc[mt][nt] = __builtin_amdgcn_mfma_f32_16x16x32_bf16(af[mt], bfr[nt], acc[mt][nt], 0, 0, 0);
    __syncthreads();
  }

  // ---- epilogue ----
  if constexpr (MODE == 2) {
    #pragma unroll
    for (int nt = 0; nt < 4; ++nt) {
      int n = n0 + wn + nt * 16 + lm;
      float bv = bias[n];
      #pragma unroll
      for (int mt = 0; mt < 4; ++mt)
        #pragma unroll
        for (int r = 0; r < 4; ++r)
          oo[(size_t)(m0 + wm + mt * 16 + q4 + r) * D_ + n] = acc[mt][nt][r] + bv;
    }
  } else {
    ushort* dst = (mat == 0) ? oq : (mat == 1) ? ok : ov;
    const int nm0 = n0 & 1023;
    #pragma unroll
    for (int p = 0; p < 2; ++p) {
      if ((w >> 1) == p) {
        #pragma unroll
        for (int nt = 0; nt < 4; ++nt) {
          int col = wn + nt * 16 + lm;
          float bv = bias[nm0 + col];
          #pragma unroll
          for (int mt = 0; mt < 4; ++mt)
            #pragma unroll
            for (int r = 0; r < 4; ++r)
              Es[(mt * 16 + q4 + r) * 144 + col] = f2b(acc[mt][nt][r] + bv);
        }
      }
      __syncthreads();
      #pragma unroll
      for (int i = 0; i < 4; ++i) {
        int e = t + i * 256, row = e >> 4, ch = e & 15;
        *(uint4*)&dst[(size_t)(m0 + p * 64 + row) * D_ + nm0 + ch * 8] =
            *(const uint4*)&Es[row * 144 + ch * 8];
      }
      __syncthreads();
    }
  }
}

// ---------------------------------------------------------------------------
// RoPE + relayout pass (memory-bound). Grid (32 bh, 32 s-tiles), 256 thr.
// ---------------------------------------------------------------------------
__global__ __launch_bounds__(256) void rope_pass(
    const ushort* __restrict__ qtmp, const ushort* __restrict__ ktmp,
    const ushort* __restrict__ vtmp,
    ushort* __restrict__ qfb, ushort* __restrict__ kfb,
    ushort* __restrict__ vtb) {
  __shared__ ushort T[64][72];
  const int t = threadIdx.x;
  const int bh = blockIdx.x, st = blockIdx.y;
  const int b = bh >> 4, h = bh & 15;
  const int s0 = st * 64;
  const int r = t >> 2, c0 = (t & 3) * 16;
  const int s = s0 + r;

  float cs[16], sn[16];
  const float pos = (float)s;
  #pragma unroll
  for (int j = 0; j < 16; ++j) {
    float invf = exp2f(-(float)((c0 + j) & 31) * ROPE_C);
    __sincosf(pos * invf, &sn[j], &cs[j]);
  }

  const size_t src = ((size_t)(b * S_ + s)) * D_ + h * 64 + c0;
  const size_t dstqk = ((size_t)bh * S_ + s) * DK_ + c0;

  #pragma unroll
  for (int tensor = 0; tensor < 2; ++tensor) {
    const ushort* in = tensor ? ktmp : qtmp;
    ushort* out = tensor ? kfb : qfb;
    const float scale = tensor ? 1.f : 0.125f;
    uint4 raw0 = *(const uint4*)&in[src];
    uint4 raw1 = *(const uint4*)&in[src + 8];
    ushort xr[16];
    *(uint4*)&xr[0] = raw0;
    *(uint4*)&xr[8] = raw1;
    float x[16];
    #pragma unroll
    for (int j = 0; j < 16; ++j) x[j] = b2f(xr[j]);
    ushort o[16];
    #pragma unroll
    for (int j = 0; j < 16; j += 2) {
      float e = x[j] * cs[j] - x[j + 1] * sn[j + 1];
      float d = x[j] * sn[j] + x[j + 1] * cs[j + 1];
      o[j] = f2b(e * scale);
      o[j + 1] = f2b(d * scale);
    }
    *(uint4*)&out[dstqk] = *(const uint4*)&o[0];
    *(uint4*)&out[dstqk + 8] = *(const uint4*)&o[8];
  }

  {
    uint4 raw0 = *(const uint4*)&vtmp[src];
    uint4 raw1 = *(const uint4*)&vtmp[src + 8];
    ushort xr[16];
    *(uint4*)&xr[0] = raw0;
    *(uint4*)&xr[8] = raw1;
    #pragma unroll
    for (int j = 0; j < 16; ++j) T[c0 + j][r] = xr[j];
    __syncthreads();
    const size_t dstv = ((size_t)bh * DK_ + r) * S_ + s0 + c0;
    *(uint4*)&vtb[dstv] = *(const uint4*)&T[r][c0];
    *(uint4*)&vtb[dstv + 8] = *(const uint4*)&T[r][c0 + 8];
  }
}

// ---------------------------------------------------------------------------
// MFMA flash attention, transposed-scores + diagonal-pair load balancing.
// Grid (32 bh, 16 qp), 256 thr. Block qp processes q-tiles {qp, 31-qp}:
// (qp+1) + (32-qp) = 33 tile-iters per block, exactly uniform.
// ---------------------------------------------------------------------------
__global__ __launch_bounds__(256) void attn_mfma(const ushort* __restrict__ qf,
                                                 const ushort* __restrict__ kf,
                                                 const ushort* __restrict__ vtf,
                                                 ushort* __restrict__ ctx) {
  __shared__ ushort Qs[64][72], Ks[64][72], Vts[64][72], Ps[64][72];

  const int t = threadIdx.x, w = t >> 6, l = t & 63;
  const int bh = blockIdx.x, qp = blockIdx.y;
  const int lm = l & 15, h8 = (l >> 4) * 8, q4 = (l >> 4) * 4, w16 = w * 16;
  const size_t base = (size_t)bh * S_ * DK_;
  const int b = bh >> 4, h = bh & 15;

  #pragma unroll
  for (int pass = 0; pass < 2; ++pass) {
    const int qt = pass ? (31 - qp) : qp;
    const int i0 = qt * 64;

    #pragma unroll
    for (int i = 0; i < 2; ++i) {
      int g = t + i * 256, r = g >> 3, c = (g & 7) * 8;
      *(uint4*)&Qs[r][c] = *(const uint4*)&qf[base + (size_t)(i0 + r) * DK_ + c];
    }

    f4 O[4];
    #pragma unroll
    for (int i = 0; i < 4; ++i) O[i] = (f4){0.f, 0.f, 0.f, 0.f};
    float m_ = -1e30f, l_ = 0.f;  // state for Q-row w16 + lm

    for (int jt = 0; jt <= qt; ++jt) {
      const int j0 = jt * 64;
      #pragma unroll
      for (int i = 0; i < 2; ++i) {
        int g = t + i * 256, r = g >> 3, c = (g & 7) * 8;
        *(uint4*)&Ks[r][c] = *(const uint4*)&kf[base + (size_t)(j0 + r) * DK_ + c];
        *(uint4*)&Vts[r][c] = *(const uint4*)&vtf[base + (size_t)r * S_ + j0 + c];
      }
      __syncthreads();  // covers Q staging too

      // S^T = K @ Q^T : rows (q4+r) = keys, cols (lm) = Q-rows
      s8 bq0 = *(const s8*)&Qs[w16 + lm][h8];
      s8 bq1 = *(const s8*)&Qs[w16 + lm][h8 + 32];
      f4 st[4];
      #pragma unroll
      for (int nt = 0; nt < 4; ++nt) {
        s8 a0 = *(const s8*)&Ks[nt * 16 + lm][h8];
        s8 a1 = *(const s8*)&Ks[nt * 16 + lm][h8 + 32];
        f4 a = (f4){0.f, 0.f, 0.f, 0.f};
        a = __builtin_amdgcn_mfma_f32_16x16x32_bf16(a0, bq0, a, 0, 0, 0);
        a = __builtin_amdgcn_mfma_f32_16x16x32_bf16(a1, bq1, a, 0, 0, 0);
        st[nt] = a;
      }
      if (jt == qt) {  // causal: key nt*16+q4+r vs qrow w16+lm
        #pragma unroll
        for (int nt = 0; nt < 4; ++nt)
          #pragma unroll
          for (int r = 0; r < 4; ++r)
            if (nt * 16 + q4 + r > w16 + lm) st[nt][r] = -1e30f;
      }
      // row max: 15 in-reg + 2 shfl
      float pm = st[0][0];
      #pragma unroll
      for (int nt = 0; nt < 4; ++nt)
        #pragma unroll
        for (int r = 0; r < 4; ++r) pm = fmaxf(pm, st[nt][r]);
      pm = fmaxf(pm, __shfl_xor(pm, 16));
      pm = fmaxf(pm, __shfl_xor(pm, 32));
      float mn = fmaxf(m_, pm);
      float alpha = exp2f((m_ - mn) * LOG2E);
      m_ = mn;
      // exp + row sum
      float ps = 0.f;
      #pragma unroll
      for (int nt = 0; nt < 4; ++nt)
        #pragma unroll
        for (int r = 0; r < 4; ++r) {
          float p = exp2f((st[nt][r] - mn) * LOG2E);
          st[nt][r] = p;
          ps += p;
        }
      ps += __shfl_xor(ps, 16);
      ps += __shfl_xor(ps, 32);
      l_ = l_ * alpha + ps;
      // P -> LDS A-layout [qrow][key]: 4x packed 8B stores
      #pragma unroll
      for (int nt = 0; nt < 4; ++nt) {
        ushort pk[4] = {f2b(st[nt][0]), f2b(st[nt][1]), f2b(st[nt][2]), f2b(st[nt][3])};
        *(uint2*)&Ps[w16 + lm][nt * 16 + q4] = *(const uint2*)pk;
      }
      // alpha for O rows q4+r (held at lanes 0..15)
      float ar[4];
      #pragma unroll
      for (int r = 0; r < 4; ++r) ar[r] = __shfl(alpha, q4 + r);
      #pragma unroll
      for (int nt = 0; nt < 4; ++nt)
        #pragma unroll
        for (int r = 0; r < 4; ++r) O[nt][r] *= ar[r];
      // PV
      s8 ap0 = *(const s8*)&Ps[w16 + lm][h8];
      s8 ap1 = *(const s8*)&Ps[w16 + lm][h8 + 32];
      #pragma unroll
      for (int nt = 0; nt < 4; ++nt) {
        s8 v0 = *(const s8*)&Vts[nt * 16 + lm][h8];
        s8 v1 = *(const s8*)&Vts[nt * 16 + lm][h8 + 32];
        O[nt] = __builtin_amdgcn_mfma_f32_16x16x32_bf16(ap0, v0, O[nt], 0, 0, 0);
        O[nt] = __builtin_amdgcn_mfma_f32_16x16x32_bf16(ap1, v1, O[nt], 0, 0, 0);
      }
      __syncthreads();
    }

    // epilogue: 1/l via shfl, stage in Qs, coalesced 16B stores
    float il[4];
    #pragma unroll
    for (int r = 0; r < 4; ++r) {
      float lr = __shfl(l_, q4 + r);
      il[r] = 1.f / lr;
    }
    #pragma unroll
    for (int nt = 0; nt < 4; ++nt)
      #pragma unroll
      for (int r = 0; r < 4; ++r)
        Qs[w16 + q4 + r][nt * 16 + lm] = f2b(O[nt][r] * il[r]);
    __syncthreads();
    #pragma unroll
    for (int i = 0; i < 2; ++i) {
      int e = t + i * 256;
      int row = e >> 3, ch = e & 7;
      int s = i0 + row;
      *(uint4*)&ctx[((size_t)(b * S_ + s)) * D_ + h * 64 + ch * 8] =
          *(const uint4*)&Qs[row][ch * 8];
    }
    __syncthreads();  // Qs reused by next pass
  }
}

// ---------------------------------------------------------------------------
extern "C" void kernel_launch(void* const* d_in, const int* in_sizes, int n_in,
                              void* d_out, int out_size, void* d_ws, size_t ws_size,
                              hipStream_t stream) {
  const float* q_in = (const float*)d_in[0];
  const float* k_in = (const float*)d_in[1];
  const float* v_in = (const float*)d_in[2];
  const float* Wq = (const float*)d_in[3];
  const float* bq = (const float*)d_in[4];
  const float* Wk = (const float*)d_in[5];
  const float* bk = (const float*)d_in[6];
  const float* Wv = (const float*)d_in[7];
  const float* bv = (const float*)d_in[8];
  const float* Wo = (const float*)d_in[9];
  const float* bo = (const float*)d_in[10];

  const size_t NE = (size_t)B_ * S_ * D_;  // 4,194,304
  ushort* Xbq = (ushort*)d_ws;
  ushort* Xbk = Xbq + NE;
  ushort* Xbv = Xbk + NE;
  ushort* Wtqkv = Xbv + NE;              // [3072][1024] bf16
  ushort* Wto = Wtqkv + 3 * 1024 * 1024;
  ushort* qtmp = Wto + 1024 * 1024;      // dense [4096][1024] bf16
  ushort* ktmp = qtmp + NE;
  ushort* vtmp = ktmp + NE;
  ushort* qfb = vtmp + NE;               // [bh][s][dk]
  ushort* kfb = qfb + NE;
  ushort* vtb = kfb + NE;                // [bh][dk][s]
  ushort* ctxb = qtmp;                   // alias: qtmp dead after rope_pass

  conv_x<<<2048, 256, 0, stream>>>(q_in, Xbq);
  conv_x<<<2048, 256, 0, stream>>>(k_in, Xbk);
  conv_x<<<2048, 256, 0, stream>>>(v_in, Xbv);
  transpose_w<<<dim3(16, 16), 256, 0, stream>>>(Wq, Wtqkv);
  transpose_w<<<dim3(16, 16), 256, 0, stream>>>(Wk, Wtqkv + 1024 * 1024);
  transpose_w<<<dim3(16, 16), 256, 0, stream>>>(Wv, Wtqkv + 2 * 1024 * 1024);
  transpose_w<<<dim3(16, 16), 256, 0, stream>>>(Wo, Wto);

  gemm_mfma<0><<<dim3(32, 24), 256, 0, stream>>>(
      Xbq, Xbk, Xbv, Wtqkv, bq, bk, bv, qtmp, ktmp, vtmp, nullptr);

  rope_pass<<<dim3(32, 32), 256, 0, stream>>>(qtmp, ktmp, vtmp, qfb, kfb, vtb);

  attn_mfma<<<dim3(32, 16), 256, 0, stream>>>(qfb, kfb, vtb, ctxb);

  gemm_mfma<2><<<dim3(32, 8), 256, 0, stream>>>(
      ctxb, ctxb, ctxb, Wto, bo, bo, bo, nullptr, nullptr, nullptr,
      (float*)d_out);
}